// Round 5
// baseline (141.792 us; speedup 1.0000x reference)
//
#include <hip/hip_runtime.h>
#include <hip/hip_bf16.h>

typedef unsigned short u16;
typedef unsigned int   u32;
typedef __attribute__((ext_vector_type(8))) short bf16x8;
typedef __attribute__((ext_vector_type(4))) float f32x4;

#define SCALE 0.08838834764831845f                 // 1/sqrt(2*64)
#define SCLOG 0.12752040542575836f                 // SCALE * log2(e)

__device__ inline u16 f2bf(float f) {
  u32 u = __builtin_bit_cast(u32, f);
  u = (u + 0x7FFFu + ((u >> 16) & 1u)) >> 16;      // RNE
  return (u16)u;
}
__device__ inline float bf2f(u16 b) {
  u32 u = (u32)b << 16;
  return __builtin_bit_cast(float, u);
}

// ---------------------------------------------------------------------------
// fp32 -> bf16 bulk convert (x and x_knowledge). grid (1024, 2), 8 elems/thr.
// ---------------------------------------------------------------------------
__global__ __launch_bounds__(256) void cvt_bf16(const float* __restrict__ a,
                                                const float* __restrict__ b,
                                                u16* __restrict__ oa,
                                                u16* __restrict__ ob) {
  const float* in = blockIdx.y ? b : a;
  u16* out = blockIdx.y ? ob : oa;
  const int i = (blockIdx.x * 256 + threadIdx.x) * 8;
  float4 f0 = *(const float4*)(in + i);
  float4 f1 = *(const float4*)(in + i + 4);
  alignas(16) u16 t[8] = {f2bf(f0.x), f2bf(f0.y), f2bf(f0.z), f2bf(f0.w),
                          f2bf(f1.x), f2bf(f1.y), f2bf(f1.z), f2bf(f1.w)};
  *(uint4*)(out + i) = *(const uint4*)t;
}

// ---------------------------------------------------------------------------
// Weight transpose Wt[z][n][k] = W[z][k][n] (fp32->bf16); slots 5,7 scaled
// by SCALE*log2e (folds attn scale + exp->exp2 into Q,Qf projections).
// ---------------------------------------------------------------------------
struct TPtrs { const float* p[10]; };

__global__ __launch_bounds__(256) void transposeW(TPtrs ptrs, u16* __restrict__ out) {
  __shared__ u16 ts[64][65];
  const float sc = (blockIdx.z == 5 || blockIdx.z == 7) ? SCLOG : 1.0f;
  const float* in = ptrs.p[blockIdx.z];
  u16* o = out + (size_t)blockIdx.z * 262144;
  const int t = threadIdx.x;
  const int k0 = blockIdx.y * 64, n0 = blockIdx.x * 64;
  for (int pp = 0; pp < 16; ++pp) {
    int id = t + 256 * pp; int r = id >> 6, c = id & 63;
    ts[r][c] = f2bf(in[(size_t)(k0 + r) * 512 + n0 + c] * sc);
  }
  __syncthreads();
  for (int pp = 0; pp < 16; ++pp) {
    int id = t + 256 * pp; int r = id >> 6, c = id & 63;
    o[(size_t)(n0 + r) * 512 + k0 + c] = ts[c][r];
  }
}

struct BPtrs { const float* p[10]; };

__global__ __launch_bounds__(512) void biasPack(BPtrs bp, float* __restrict__ out) {
  const int z = blockIdx.x, n = threadIdx.x;
  const float sc = (z == 5 || z == 7) ? SCLOG : 1.0f;
  out[z * 512 + n] = bp.p[z][n] * sc;
}

// ---------------------------------------------------------------------------
// Per-head V transpose: v1 (2048,64) -> vt (64,2048) per head-block.
// The raw-reshape head split makes each head's block contiguous, so this is
// a verbatim block transpose. grid (32,16).
// ---------------------------------------------------------------------------
__global__ __launch_bounds__(256) void transposeV(const u16* __restrict__ v1,
                                                  u16* __restrict__ vt) {
  __shared__ u16 ts[64][65];
  const size_t base = (size_t)blockIdx.y * 131072;
  const u16* in = v1 + base;
  u16* out = vt + base;
  const int l0 = blockIdx.x * 64;
  const int t = threadIdx.x;
  const int r = t >> 3, c8 = (t & 7) * 8;
  for (int pp = 0; pp < 2; ++pp) {
    int rr = r + pp * 32;
    *(uint4*)&ts[rr][c8] = *(const uint4*)&in[(size_t)(l0 + rr) * 64 + c8];
  }
  __syncthreads();
  for (int pp = 0; pp < 2; ++pp) {
    int d = r + pp * 32;
    alignas(16) u16 tmp[8];
    #pragma unroll
    for (int i = 0; i < 8; ++i) tmp[i] = ts[c8 + i][d];
    *(uint4*)&out[(size_t)d * 2048 + l0 + c8] = *(const uint4*)tmp;
  }
}

// ---------------------------------------------------------------------------
// GEMM: 128x128 tile, BK=64, 4 waves (2x2) of 64x64. 2-phase dbuf, reg-staged,
// XOR-swizzled LDS. Wt is one (5120 x 512) matrix; wrow = wrow0+z*zstride+
// blockIdx.x*128. A switches to Ax at tile xsplit (stage-1 fusion).
// ---------------------------------------------------------------------------
struct GemmBatch {
  const u16* A[4];
  const u16* Ax;
  int xsplit;
  void* out[5];        // indexed by (wrow>>9) - (wrow0>>9)
  int wrow0, zstride;
};

template <typename TOUT>
__global__ __launch_bounds__(256, 2) void gemm3(GemmBatch gb,
    const u16* __restrict__ Wt, const float* __restrict__ biasP) {
  const int tx = blockIdx.x, z = blockIdx.z;
  const u16* A = (tx < gb.xsplit) ? gb.A[z] : gb.Ax;
  const int wrow = gb.wrow0 + z * gb.zstride + tx * 128;
  const int m0 = blockIdx.y * 128;
  const u16* B = Wt + (size_t)wrow * 512;
  const float* bias = biasP + wrow;

  const int t = threadIdx.x, wid = t >> 6, lane = t & 63;
  const int lg = lane >> 4, ln = lane & 15;
  const int wr = wid >> 1, wc = wid & 1;

  __shared__ u16 As[2][128][64];
  __shared__ u16 Bs[2][128][64];

  const int srow = t >> 3, sch = t & 7;
  const int sw = (sch ^ (srow & 7)) * 8;
  const u16* Asrc = A + (size_t)(m0 + srow) * 512 + sch * 8;
  const u16* Bsrc = B + (size_t)srow * 512 + sch * 8;

  uint4 ra[4], rb[4];
  #pragma unroll
  for (int p = 0; p < 4; ++p) {
    ra[p] = *(const uint4*)(Asrc + p * 32 * 512);
    rb[p] = *(const uint4*)(Bsrc + p * 32 * 512);
  }
  #pragma unroll
  for (int p = 0; p < 4; ++p) {
    *(uint4*)&As[0][srow + 32 * p][sw] = ra[p];
    *(uint4*)&Bs[0][srow + 32 * p][sw] = rb[p];
  }
  __syncthreads();

  f32x4 acc[4][4];
  #pragma unroll
  for (int i = 0; i < 4; ++i)
    #pragma unroll
    for (int j = 0; j < 4; ++j)
      #pragma unroll
      for (int r = 0; r < 4; ++r) acc[i][j][r] = 0.0f;

  int cur = 0;
  for (int kt = 0; kt < 8; ++kt) {
    if (kt < 7) {
      const int ko = (kt + 1) * 64;
      #pragma unroll
      for (int p = 0; p < 4; ++p) {
        ra[p] = *(const uint4*)(Asrc + ko + p * 32 * 512);
        rb[p] = *(const uint4*)(Bsrc + ko + p * 32 * 512);
      }
    }
    #pragma unroll
    for (int ck = 0; ck < 2; ++ck) {
      bf16x8 af[4], bfr[4];
      #pragma unroll
      for (int mi = 0; mi < 4; ++mi) {
        const int r = wr * 64 + mi * 16 + ln;
        af[mi] = *(const bf16x8*)&As[cur][r][((ck * 4 + lg) ^ (r & 7)) * 8];
      }
      #pragma unroll
      for (int ni = 0; ni < 4; ++ni) {
        const int r = wc * 64 + ni * 16 + ln;
        bfr[ni] = *(const bf16x8*)&Bs[cur][r][((ck * 4 + lg) ^ (r & 7)) * 8];
      }
      #pragma unroll
      for (int mi = 0; mi < 4; ++mi)
        #pragma unroll
        for (int ni = 0; ni < 4; ++ni)
          acc[mi][ni] = __builtin_amdgcn_mfma_f32_16x16x32_bf16(
              af[mi], bfr[ni], acc[mi][ni], 0, 0, 0);
    }
    if (kt < 7) {
      #pragma unroll
      for (int p = 0; p < 4; ++p) {
        *(uint4*)&As[cur ^ 1][srow + 32 * p][sw] = ra[p];
        *(uint4*)&Bs[cur ^ 1][srow + 32 * p][sw] = rb[p];
      }
      __syncthreads();
      cur ^= 1;
    }
  }

  TOUT* C = (TOUT*)gb.out[(wrow >> 9) - (gb.wrow0 >> 9)];
  const int nbase = wrow & 511;
  #pragma unroll
  for (int ni = 0; ni < 4; ++ni) {
    const int colw = wc * 64 + ni * 16 + ln;
    const float bv = bias[colw];
    const int col = nbase + colw;
    #pragma unroll
    for (int mi = 0; mi < 4; ++mi)
      #pragma unroll
      for (int r = 0; r < 4; ++r) {
        const int row = m0 + wr * 64 + mi * 16 + 4 * lg + r;
        const float val = acc[mi][ni][r] + bv;
        if constexpr (sizeof(TOUT) == 4) C[(size_t)row * 512 + col] = val;
        else                             C[(size_t)row * 512 + col] = f2bf(val);
      }
  }
}

// ---------------------------------------------------------------------------
// Flash attention, KV-split x2: 512 blocks (2/CU -> 2 waves/SIMD), each
// handles 128 Q rows x 1024 KV. Writes unnormalized O (bf16) + (m,l) per row.
// QBLK=128 (4 waves x 32 rows), KVBLK=64, 2-phase dbuf, defer-max (THR=11,
// log2 domain), Q pre-scaled by SCALE*log2e.
// ---------------------------------------------------------------------------
__global__ __launch_bounds__(256) void attn4(
    const u16* __restrict__ q2, const u16* __restrict__ k2,
    const u16* __restrict__ qf2, const u16* __restrict__ kf2,
    const u16* __restrict__ vtg, u16* __restrict__ opart,
    float2* __restrict__ mlbuf) {
  const int id = blockIdx.x;
  const int nid = (id & 7) * 64 + (id >> 3);   // XCD-bijective: 2 heads/XCD
  const int split = nid & 1;
  const int qp = nid >> 1;
  const int qt = qp & 15, bh = qp >> 4;
  const size_t base = (size_t)bh * 131072;
  const int kv0 = split * 1024;

  const u16* Q  = q2  + base;
  const u16* Qf = qf2 + base;
  u16* Op = opart + (size_t)split * 2097152 + base;

  const int t = threadIdx.x, wid = t >> 6, lane = t & 63;
  const int lg = lane >> 4, ln = lane & 15;
  const int r0 = qt * 128 + wid * 32;          // this wave's 32 Q rows (local)

  __shared__ u16 K_s [2][64][64];
  __shared__ u16 Kf_s[2][64][64];
  __shared__ u16 Vt_s[2][64][64];
  __shared__ u16 P_s [4][32][64];

  const int srow = t >> 3, sch = t & 7;
  const int sw = (sch ^ (srow & 7)) * 8;
  const u16* Ksrc  = k2  + base + (size_t)(kv0 + srow) * 64 + sch * 8;
  const u16* Kfsrc = kf2 + base + (size_t)(kv0 + srow) * 64 + sch * 8;
  const u16* Vsrc  = vtg + base + (size_t)srow * 2048 + kv0 + sch * 8;

  bf16x8 aq[2][4];
  #pragma unroll
  for (int mi = 0; mi < 2; ++mi) {
    const int row = r0 + mi * 16 + ln;
    aq[mi][0] = *(const bf16x8*)&Q [row * 64 +      lg * 8];
    aq[mi][1] = *(const bf16x8*)&Q [row * 64 + 32 + lg * 8];
    aq[mi][2] = *(const bf16x8*)&Qf[row * 64 +      lg * 8];
    aq[mi][3] = *(const bf16x8*)&Qf[row * 64 + 32 + lg * 8];
  }

  f32x4 oacc[2][4];
  #pragma unroll
  for (int mi = 0; mi < 2; ++mi)
    #pragma unroll
    for (int df = 0; df < 4; ++df)
      #pragma unroll
      for (int r = 0; r < 4; ++r) oacc[mi][df][r] = 0.0f;
  float m_run[2][4], l_par[2][4];
  #pragma unroll
  for (int mi = 0; mi < 2; ++mi)
    #pragma unroll
    for (int r = 0; r < 4; ++r) { m_run[mi][r] = -1e30f; l_par[mi][r] = 0.0f; }

  // prologue: stage tile 0
  uint4 rk0 = *(const uint4*)(Ksrc);
  uint4 rk1 = *(const uint4*)(Ksrc + 2048);
  uint4 rf0 = *(const uint4*)(Kfsrc);
  uint4 rf1 = *(const uint4*)(Kfsrc + 2048);
  uint4 rv0 = *(const uint4*)(Vsrc);
  uint4 rv1 = *(const uint4*)(Vsrc + 65536);
  *(uint4*)&K_s [0][srow][sw] = rk0;  *(uint4*)&K_s [0][srow + 32][sw] = rk1;
  *(uint4*)&Kf_s[0][srow][sw] = rf0;  *(uint4*)&Kf_s[0][srow + 32][sw] = rf1;
  *(uint4*)&Vt_s[0][srow][sw] = rv0;  *(uint4*)&Vt_s[0][srow + 32][sw] = rv1;
  __syncthreads();

  int cur = 0;
  for (int kt = 0; kt < 16; ++kt) {
    if (kt < 15) {
      const int ko = (kt + 1) * 4096;
      rk0 = *(const uint4*)(Ksrc  + ko);
      rk1 = *(const uint4*)(Ksrc  + ko + 2048);
      rf0 = *(const uint4*)(Kfsrc + ko);
      rf1 = *(const uint4*)(Kfsrc + ko + 2048);
      rv0 = *(const uint4*)(Vsrc  + (kt + 1) * 64);
      rv1 = *(const uint4*)(Vsrc  + (kt + 1) * 64 + 65536);
    }

    // ---- S = Q K^T + Qf Kf^T (pre-scaled, log2 domain) ----
    f32x4 s[2][4];
    #pragma unroll
    for (int cf = 0; cf < 4; ++cf) {
      const int n = cf * 16 + ln;
      const int sx = n & 7;
      bf16x8 b0 = *(const bf16x8*)&K_s [cur][n][((0 + lg) ^ sx) * 8];
      bf16x8 b1 = *(const bf16x8*)&K_s [cur][n][((4 + lg) ^ sx) * 8];
      bf16x8 b2 = *(const bf16x8*)&Kf_s[cur][n][((0 + lg) ^ sx) * 8];
      bf16x8 b3 = *(const bf16x8*)&Kf_s[cur][n][((4 + lg) ^ sx) * 8];
      #pragma unroll
      for (int mi = 0; mi < 2; ++mi) {
        f32x4 a;
        #pragma unroll
        for (int r = 0; r < 4; ++r) a[r] = 0.0f;
        a = __builtin_amdgcn_mfma_f32_16x16x32_bf16(aq[mi][0], b0, a, 0, 0, 0);
        a = __builtin_amdgcn_mfma_f32_16x16x32_bf16(aq[mi][1], b1, a, 0, 0, 0);
        a = __builtin_amdgcn_mfma_f32_16x16x32_bf16(aq[mi][2], b2, a, 0, 0, 0);
        a = __builtin_amdgcn_mfma_f32_16x16x32_bf16(aq[mi][3], b3, a, 0, 0, 0);
        s[mi][cf] = a;
      }
    }

    // ---- defer-max online softmax ----
    float smax[2][4];
    bool viol = false;
    #pragma unroll
    for (int mi = 0; mi < 2; ++mi)
      #pragma unroll
      for (int r = 0; r < 4; ++r) {
        smax[mi][r] = fmaxf(fmaxf(s[mi][0][r], s[mi][1][r]),
                            fmaxf(s[mi][2][r], s[mi][3][r]));
        viol = viol || (smax[mi][r] > m_run[mi][r] + 11.0f);
      }
    if (__any(viol)) {
      #pragma unroll
      for (int off = 1; off < 16; off <<= 1)
        #pragma unroll
        for (int mi = 0; mi < 2; ++mi)
          #pragma unroll
          for (int r = 0; r < 4; ++r)
            smax[mi][r] = fmaxf(smax[mi][r], __shfl_xor(smax[mi][r], off, 64));
      #pragma unroll
      for (int mi = 0; mi < 2; ++mi)
        #pragma unroll
        for (int r = 0; r < 4; ++r) {
          const float mnew = fmaxf(m_run[mi][r], smax[mi][r]);
          const float corr = exp2f(m_run[mi][r] - mnew);
          m_run[mi][r] = mnew;
          l_par[mi][r] *= corr;
          #pragma unroll
          for (int df = 0; df < 4; ++df) oacc[mi][df][r] *= corr;
        }
    }
    #pragma unroll
    for (int mi = 0; mi < 2; ++mi)
      #pragma unroll
      for (int cf = 0; cf < 4; ++cf) {
        const int col = cf * 16 + ln;
        #pragma unroll
        for (int r = 0; r < 4; ++r) {
          const int rr = 4 * lg + r;
          const float p = exp2f(s[mi][cf][r] - m_run[mi][r]);
          l_par[mi][r] += p;
          P_s[wid][mi * 16 + rr][col ^ ((rr & 7) * 8)] =
              __builtin_bit_cast(u16, __float2bfloat16(p));
        }
      }

    // ---- O += P @ V ----
    #pragma unroll
    for (int kc = 0; kc < 2; ++kc) {
      const int kk = kc * 32 + lg * 8;
      bf16x8 ap0 = *(const bf16x8*)&P_s[wid][ln]     [kk ^ ((ln & 7) * 8)];
      bf16x8 ap1 = *(const bf16x8*)&P_s[wid][16 + ln][kk ^ ((ln & 7) * 8)];
      #pragma unroll
      for (int df = 0; df < 4; ++df) {
        const int n = df * 16 + ln;
        bf16x8 bv = *(const bf16x8*)&Vt_s[cur][n][((kc * 4 + lg) ^ (n & 7)) * 8];
        oacc[0][df] = __builtin_amdgcn_mfma_f32_16x16x32_bf16(ap0, bv, oacc[0][df], 0, 0, 0);
        oacc[1][df] = __builtin_amdgcn_mfma_f32_16x16x32_bf16(ap1, bv, oacc[1][df], 0, 0, 0);
      }
    }

    if (kt < 15) {
      *(uint4*)&K_s [cur ^ 1][srow][sw] = rk0;  *(uint4*)&K_s [cur ^ 1][srow + 32][sw] = rk1;
      *(uint4*)&Kf_s[cur ^ 1][srow][sw] = rf0;  *(uint4*)&Kf_s[cur ^ 1][srow + 32][sw] = rf1;
      *(uint4*)&Vt_s[cur ^ 1][srow][sw] = rv0;  *(uint4*)&Vt_s[cur ^ 1][srow + 32][sw] = rv1;
      __syncthreads();
      cur ^= 1;
    }
  }

  // epilogue: reduce l across 16 lanes; write unnormalized O + (m,l)
  #pragma unroll
  for (int off = 1; off < 16; off <<= 1)
    #pragma unroll
    for (int mi = 0; mi < 2; ++mi)
      #pragma unroll
      for (int r = 0; r < 4; ++r)
        l_par[mi][r] += __shfl_xor(l_par[mi][r], off, 64);

  #pragma unroll
  for (int mi = 0; mi < 2; ++mi)
    #pragma unroll
    for (int df = 0; df < 4; ++df)
      #pragma unroll
      for (int r = 0; r < 4; ++r) {
        const int row = r0 + mi * 16 + 4 * lg + r;
        const int col = df * 16 + ln;
        Op[(size_t)row * 64 + col] = f2bf(oacc[mi][df][r]);
      }
  if (ln == 0) {
    #pragma unroll
    for (int mi = 0; mi < 2; ++mi)
      #pragma unroll
      for (int r = 0; r < 4; ++r) {
        const int grow = bh * 2048 + r0 + mi * 16 + 4 * lg + r;
        mlbuf[split * 32768 + grow] = make_float2(m_run[mi][r], l_par[mi][r]);
      }
  }
}

// ---------------------------------------------------------------------------
// Combine the two KV-split partials: out = sum_i O_i*a_i / sum_i l_i*a_i.
// grid 1024 x 256, 8 cols/thread.
// ---------------------------------------------------------------------------
__global__ __launch_bounds__(256) void combine(
    const u16* __restrict__ opart, const float2* __restrict__ mlbuf,
    u16* __restrict__ att) {
  const int gid = blockIdx.x * 256 + threadIdx.x;
  const int row = gid >> 3, c8 = (gid & 7) * 8;
  const float2 ml1 = mlbuf[row];
  const float2 ml2 = mlbuf[32768 + row];
  const float mx = fmaxf(ml1.x, ml2.x);
  const float a1 = exp2f(ml1.x - mx), a2 = exp2f(ml2.x - mx);
  const float inv = 1.0f / (ml1.y * a1 + ml2.y * a2);
  const float w1 = a1 * inv, w2 = a2 * inv;
  uint4 o1 = *(const uint4*)&opart[(size_t)row * 64 + c8];
  uint4 o2 = *(const uint4*)&opart[2097152 + (size_t)row * 64 + c8];
  const u16* p1 = (const u16*)&o1;
  const u16* p2 = (const u16*)&o2;
  alignas(16) u16 ot[8];
  #pragma unroll
  for (int i = 0; i < 8; ++i)
    ot[i] = f2bf(bf2f(p1[i]) * w1 + bf2f(p2[i]) * w2);
  *(uint4*)&att[(size_t)row * 64 + c8] = *(const uint4*)ot;
}

// ---------------------------------------------------------------------------
extern "C" void kernel_launch(void* const* d_in, const int* in_sizes, int n_in,
                              void* d_out, int out_size, void* d_ws, size_t ws_size,
                              hipStream_t stream) {
  const float* x    = (const float*)d_in[0];
  const float* xk   = (const float*)d_in[1];
  const float* Wv   = (const float*)d_in[2];  const float* bv   = (const float*)d_in[3];
  const float* Wk   = (const float*)d_in[4];  const float* bk   = (const float*)d_in[5];
  const float* Wq   = (const float*)d_in[6];  const float* bq   = (const float*)d_in[7];
  const float* Wkf  = (const float*)d_in[8];  const float* bkf  = (const float*)d_in[9];
  const float* Wqf  = (const float*)d_in[10]; const float* bqf  = (const float*)d_in[11];
  const float* Wq2  = (const float*)d_in[12]; const float* bq2  = (const float*)d_in[13];
  const float* Wk2  = (const float*)d_in[14]; const float* bk2  = (const float*)d_in[15];
  const float* Wqf2 = (const float*)d_in[16]; const float* bqf2 = (const float*)d_in[17];
  const float* Wkf2 = (const float*)d_in[18]; const float* bkf2 = (const float*)d_in[19];
  const float* Wo   = (const float*)d_in[20]; const float* bo   = (const float*)d_in[21];

  u16* ws = (u16*)d_ws;
  u16* Wt = ws;                                   // 10 x 262144 u16 (5120x512)
  float* biasP = (float*)(ws + 2621440);          // 5120 f32
  u16* bufs = ws + 2621440 + 10240;
  const size_t BUF = 2097152;
  u16* v1  = bufs + 0 * BUF;   // stage-1 v; later att (combine output)
  u16* k1  = bufs + 1 * BUF;   // stage-1 k
  u16* q1  = bufs + 2 * BUF;   // stage-1 q; later vt (dead after stage-2)
  u16* kf1 = bufs + 3 * BUF;   // stage-1 kf; later O_part split 0
  u16* qf1 = bufs + 4 * BUF;   // stage-1 qf; later O_part split 1 (contig)
  u16* q2  = bufs + 5 * BUF;   // xb, then stage-2 q
  u16* k2  = bufs + 6 * BUF;   // xkb, then stage-2 k
  u16* qf2 = bufs + 7 * BUF;
  u16* kf2 = bufs + 8 * BUF;
  float2* mlbuf = (float2*)(bufs + 9 * BUF);      // 2 x 32768 float2

  cvt_bf16<<<dim3(1024, 2), 256, 0, stream>>>(x, xk, q2, k2);

  TPtrs tp;
  tp.p[0] = Wv;  tp.p[1] = Wk;  tp.p[2] = Wq;   tp.p[3] = Wkf;  tp.p[4] = Wqf;
  tp.p[5] = Wq2; tp.p[6] = Wk2; tp.p[7] = Wqf2; tp.p[8] = Wkf2; tp.p[9] = Wo;
  transposeW<<<dim3(8, 8, 10), 256, 0, stream>>>(tp, Wt);

  BPtrs bp;
  bp.p[0] = bv;  bp.p[1] = bk;  bp.p[2] = bq;   bp.p[3] = bkf;  bp.p[4] = bqf;
  bp.p[5] = bq2; bp.p[6] = bk2; bp.p[7] = bqf2; bp.p[8] = bkf2; bp.p[9] = bo;
  biasPack<<<dim3(10), 512, 0, stream>>>(bp, biasP);

  // stage-1 fused (x and xk in one launch): v,k,q from x; kf,qf from xk
  GemmBatch g1 = {};
  g1.A[0] = q2;  g1.Ax = k2;  g1.xsplit = 12;
  g1.out[0] = v1; g1.out[1] = k1; g1.out[2] = q1; g1.out[3] = kf1; g1.out[4] = qf1;
  g1.wrow0 = 0; g1.zstride = 0;
  gemm3<u16><<<dim3(20, 32, 1), 256, 0, stream>>>(g1, Wt, biasP);

  // stage-2 batched: {q1,k1,qf1,kf1} @ {Wq2,Wk2,Wqf2,Wkf2} -> {q2,k2,qf2,kf2}
  GemmBatch g3 = {};
  g3.A[0] = q1; g3.A[1] = k1; g3.A[2] = qf1; g3.A[3] = kf1;
  g3.Ax = q1; g3.xsplit = 100;
  g3.out[0] = q2; g3.out[1] = k2; g3.out[2] = qf2; g3.out[3] = kf2;
  g3.wrow0 = 2560; g3.zstride = 512;
  gemm3<u16><<<dim3(4, 32, 4), 256, 0, stream>>>(g3, Wt, biasP);

  // V transpose per head-block (v1 -> q1; q1 dead after stage-2)
  transposeV<<<dim3(32, 16), 256, 0, stream>>>(v1, q1);

  // attention, KV-split x2: O_part into kf1|qf1 (contiguous 2 x BUF)
  attn4<<<dim3(512), 256, 0, stream>>>(q2, k2, qf2, kf2, q1, kf1, mlbuf);

  // combine partials -> att (v1)
  combine<<<dim3(1024), 256, 0, stream>>>(kf1, mlbuf, v1);

  // final: att @ Wo + bo -> d_out (fp32)
  GemmBatch g4 = {};
  g4.A[0] = v1; g4.Ax = v1; g4.xsplit = 100;
  g4.out[0] = d_out;
  g4.wrow0 = 4608; g4.zstride = 0;
  gemm3<float><<<dim3(4, 32, 1), 256, 0, stream>>>(g4, Wt, biasP);
}

// Round 6
// 119.570 us; speedup vs baseline: 1.1859x; 1.1859x over previous
//
#include <hip/hip_runtime.h>
#include <hip/hip_bf16.h>

typedef unsigned short u16;
typedef unsigned int   u32;
typedef __attribute__((ext_vector_type(8))) short bf16x8;
typedef __attribute__((ext_vector_type(4))) float f32x4;

#define SCALE 0.08838834764831845f                 // 1/sqrt(2*64)
#define SCLOG 0.12752040542575836f                 // SCALE * log2(e)

__device__ inline u16 f2bf(float f) {
  u32 u = __builtin_bit_cast(u32, f);
  u = (u + 0x7FFFu + ((u >> 16) & 1u)) >> 16;      // RNE
  return (u16)u;
}
__device__ inline float bf2f(u16 b) {
  u32 u = (u32)b << 16;
  return __builtin_bit_cast(float, u);
}

// ---------------------------------------------------------------------------
// fp32 -> bf16 bulk convert (x and x_knowledge). grid (1024, 2), 8 elems/thr.
// ---------------------------------------------------------------------------
__global__ __launch_bounds__(256) void cvt_bf16(const float* __restrict__ a,
                                                const float* __restrict__ b,
                                                u16* __restrict__ oa,
                                                u16* __restrict__ ob) {
  const float* in = blockIdx.y ? b : a;
  u16* out = blockIdx.y ? ob : oa;
  const int i = (blockIdx.x * 256 + threadIdx.x) * 8;
  float4 f0 = *(const float4*)(in + i);
  float4 f1 = *(const float4*)(in + i + 4);
  alignas(16) u16 t[8] = {f2bf(f0.x), f2bf(f0.y), f2bf(f0.z), f2bf(f0.w),
                          f2bf(f1.x), f2bf(f1.y), f2bf(f1.z), f2bf(f1.w)};
  *(uint4*)(out + i) = *(const uint4*)t;
}

// ---------------------------------------------------------------------------
// Weight transpose Wt[z][n][k] = W[z][k][n] (fp32->bf16); slots 5,7 scaled
// by SCALE*log2e (folds attn scale + exp->exp2 into Q,Qf projections).
// ---------------------------------------------------------------------------
struct TPtrs { const float* p[10]; };

__global__ __launch_bounds__(256) void transposeW(TPtrs ptrs, u16* __restrict__ out) {
  __shared__ u16 ts[64][65];
  const float sc = (blockIdx.z == 5 || blockIdx.z == 7) ? SCLOG : 1.0f;
  const float* in = ptrs.p[blockIdx.z];
  u16* o = out + (size_t)blockIdx.z * 262144;
  const int t = threadIdx.x;
  const int k0 = blockIdx.y * 64, n0 = blockIdx.x * 64;
  for (int pp = 0; pp < 16; ++pp) {
    int id = t + 256 * pp; int r = id >> 6, c = id & 63;
    ts[r][c] = f2bf(in[(size_t)(k0 + r) * 512 + n0 + c] * sc);
  }
  __syncthreads();
  for (int pp = 0; pp < 16; ++pp) {
    int id = t + 256 * pp; int r = id >> 6, c = id & 63;
    o[(size_t)(n0 + r) * 512 + k0 + c] = ts[c][r];
  }
}

struct BPtrs { const float* p[10]; };

__global__ __launch_bounds__(512) void biasPack(BPtrs bp, float* __restrict__ out) {
  const int z = blockIdx.x, n = threadIdx.x;
  const float sc = (z == 5 || z == 7) ? SCLOG : 1.0f;
  out[z * 512 + n] = bp.p[z][n] * sc;
}

// ---------------------------------------------------------------------------
// Per-head V transpose: v1 (2048,64) -> vt (64,2048) per head-block.
// grid (32,16).
// ---------------------------------------------------------------------------
__global__ __launch_bounds__(256) void transposeV(const u16* __restrict__ v1,
                                                  u16* __restrict__ vt) {
  __shared__ u16 ts[64][65];
  const size_t base = (size_t)blockIdx.y * 131072;
  const u16* in = v1 + base;
  u16* out = vt + base;
  const int l0 = blockIdx.x * 64;
  const int t = threadIdx.x;
  const int r = t >> 3, c8 = (t & 7) * 8;
  for (int pp = 0; pp < 2; ++pp) {
    int rr = r + pp * 32;
    *(uint4*)&ts[rr][c8] = *(const uint4*)&in[(size_t)(l0 + rr) * 64 + c8];
  }
  __syncthreads();
  for (int pp = 0; pp < 2; ++pp) {
    int d = r + pp * 32;
    alignas(16) u16 tmp[8];
    #pragma unroll
    for (int i = 0; i < 8; ++i) tmp[i] = ts[c8 + i][d];
    *(uint4*)&out[(size_t)d * 2048 + l0 + c8] = *(const uint4*)tmp;
  }
}

// ---------------------------------------------------------------------------
// GEMM: 128x128 tile, BK=64, 4 waves (2x2) of 64x64. 2-phase dbuf, reg-staged,
// XOR-swizzled LDS. Wt is one (5120 x 512) matrix; wrow = wrow0+z*zstride+
// blockIdx.x*128. A switches to Ax at tile xsplit (stage-1 fusion).
// ---------------------------------------------------------------------------
struct GemmBatch {
  const u16* A[4];
  const u16* Ax;
  int xsplit;
  void* out[5];        // indexed by (wrow>>9) - (wrow0>>9)
  int wrow0, zstride;
};

template <typename TOUT>
__global__ __launch_bounds__(256, 2) void gemm3(GemmBatch gb,
    const u16* __restrict__ Wt, const float* __restrict__ biasP) {
  const int tx = blockIdx.x, z = blockIdx.z;
  const u16* A = (tx < gb.xsplit) ? gb.A[z] : gb.Ax;
  const int wrow = gb.wrow0 + z * gb.zstride + tx * 128;
  const int m0 = blockIdx.y * 128;
  const u16* B = Wt + (size_t)wrow * 512;
  const float* bias = biasP + wrow;

  const int t = threadIdx.x, wid = t >> 6, lane = t & 63;
  const int lg = lane >> 4, ln = lane & 15;
  const int wr = wid >> 1, wc = wid & 1;

  __shared__ u16 As[2][128][64];
  __shared__ u16 Bs[2][128][64];

  const int srow = t >> 3, sch = t & 7;
  const int sw = (sch ^ (srow & 7)) * 8;
  const u16* Asrc = A + (size_t)(m0 + srow) * 512 + sch * 8;
  const u16* Bsrc = B + (size_t)srow * 512 + sch * 8;

  uint4 ra[4], rb[4];
  #pragma unroll
  for (int p = 0; p < 4; ++p) {
    ra[p] = *(const uint4*)(Asrc + p * 32 * 512);
    rb[p] = *(const uint4*)(Bsrc + p * 32 * 512);
  }
  #pragma unroll
  for (int p = 0; p < 4; ++p) {
    *(uint4*)&As[0][srow + 32 * p][sw] = ra[p];
    *(uint4*)&Bs[0][srow + 32 * p][sw] = rb[p];
  }
  __syncthreads();

  f32x4 acc[4][4];
  #pragma unroll
  for (int i = 0; i < 4; ++i)
    #pragma unroll
    for (int j = 0; j < 4; ++j)
      #pragma unroll
      for (int r = 0; r < 4; ++r) acc[i][j][r] = 0.0f;

  int cur = 0;
  for (int kt = 0; kt < 8; ++kt) {
    if (kt < 7) {
      const int ko = (kt + 1) * 64;
      #pragma unroll
      for (int p = 0; p < 4; ++p) {
        ra[p] = *(const uint4*)(Asrc + ko + p * 32 * 512);
        rb[p] = *(const uint4*)(Bsrc + ko + p * 32 * 512);
      }
    }
    #pragma unroll
    for (int ck = 0; ck < 2; ++ck) {
      bf16x8 af[4], bfr[4];
      #pragma unroll
      for (int mi = 0; mi < 4; ++mi) {
        const int r = wr * 64 + mi * 16 + ln;
        af[mi] = *(const bf16x8*)&As[cur][r][((ck * 4 + lg) ^ (r & 7)) * 8];
      }
      #pragma unroll
      for (int ni = 0; ni < 4; ++ni) {
        const int r = wc * 64 + ni * 16 + ln;
        bfr[ni] = *(const bf16x8*)&Bs[cur][r][((ck * 4 + lg) ^ (r & 7)) * 8];
      }
      #pragma unroll
      for (int mi = 0; mi < 4; ++mi)
        #pragma unroll
        for (int ni = 0; ni < 4; ++ni)
          acc[mi][ni] = __builtin_amdgcn_mfma_f32_16x16x32_bf16(
              af[mi], bfr[ni], acc[mi][ni], 0, 0, 0);
    }
    if (kt < 7) {
      #pragma unroll
      for (int p = 0; p < 4; ++p) {
        *(uint4*)&As[cur ^ 1][srow + 32 * p][sw] = ra[p];
        *(uint4*)&Bs[cur ^ 1][srow + 32 * p][sw] = rb[p];
      }
      __syncthreads();
      cur ^= 1;
    }
  }

  TOUT* C = (TOUT*)gb.out[(wrow >> 9) - (gb.wrow0 >> 9)];
  const int nbase = wrow & 511;
  #pragma unroll
  for (int ni = 0; ni < 4; ++ni) {
    const int colw = wc * 64 + ni * 16 + ln;
    const float bv = bias[colw];
    const int col = nbase + colw;
    #pragma unroll
    for (int mi = 0; mi < 4; ++mi)
      #pragma unroll
      for (int r = 0; r < 4; ++r) {
        const int row = m0 + wr * 64 + mi * 16 + 4 * lg + r;
        const float val = acc[mi][ni][r] + bv;
        if constexpr (sizeof(TOUT) == 4) C[(size_t)row * 512 + col] = val;
        else                             C[(size_t)row * 512 + col] = f2bf(val);
      }
  }
}

// ---------------------------------------------------------------------------
// Flash attention: 512 threads = 8 waves x 32 Q-rows (QBLK=256), KVBLK=64,
// KV-split x2. grid 256 = exactly 1 block/CU -> 8 waves/CU = 2/SIMD
// deterministic (intra-block TLP; no inter-block LDS co-residency gamble).
// K/Kf/Vt double-buffered (48 KiB) + per-wave P_s (32 KiB) = 80 KiB LDS.
// Defer-max (THR=11, log2 domain), Q pre-scaled by SCALE*log2e.
// Writes unnormalized O (bf16) + (m,l) per row; combine kernel merges splits.
// ---------------------------------------------------------------------------
__global__ __launch_bounds__(512) void attn5(
    const u16* __restrict__ q2, const u16* __restrict__ k2,
    const u16* __restrict__ qf2, const u16* __restrict__ kf2,
    const u16* __restrict__ vtg, u16* __restrict__ opart,
    float2* __restrict__ mlbuf) {
  const int id = blockIdx.x;
  const int nid = (id & 7) * 32 + (id >> 3);   // XCD-bijective: 2 heads/XCD
  const int split = nid & 1;
  const int qt = (nid >> 1) & 7;
  const int bh = nid >> 4;
  const size_t base = (size_t)bh * 131072;
  const int kv0 = split * 1024;

  const u16* Q  = q2  + base;
  const u16* Qf = qf2 + base;
  u16* Op = opart + (size_t)split * 2097152 + base;

  const int t = threadIdx.x, wid = t >> 6, lane = t & 63;
  const int lg = lane >> 4, ln = lane & 15;
  const int r0 = qt * 256 + wid * 32;          // this wave's 32 Q rows (local)

  __shared__ u16 K_s [2][64][64];
  __shared__ u16 Kf_s[2][64][64];
  __shared__ u16 Vt_s[2][64][64];
  __shared__ u16 P_s [8][32][64];

  const int srow = t >> 3, sch = t & 7;        // 64 rows x 8 chunks, 1 uint4/thr
  const int sw = (sch ^ (srow & 7)) * 8;
  const u16* Ksrc  = k2  + base + (size_t)(kv0 + srow) * 64 + sch * 8;
  const u16* Kfsrc = kf2 + base + (size_t)(kv0 + srow) * 64 + sch * 8;
  const u16* Vsrc  = vtg + base + (size_t)srow * 2048 + kv0 + sch * 8;

  bf16x8 aq[2][4];
  #pragma unroll
  for (int mi = 0; mi < 2; ++mi) {
    const int row = r0 + mi * 16 + ln;
    aq[mi][0] = *(const bf16x8*)&Q [row * 64 +      lg * 8];
    aq[mi][1] = *(const bf16x8*)&Q [row * 64 + 32 + lg * 8];
    aq[mi][2] = *(const bf16x8*)&Qf[row * 64 +      lg * 8];
    aq[mi][3] = *(const bf16x8*)&Qf[row * 64 + 32 + lg * 8];
  }

  f32x4 oacc[2][4];
  #pragma unroll
  for (int mi = 0; mi < 2; ++mi)
    #pragma unroll
    for (int df = 0; df < 4; ++df)
      #pragma unroll
      for (int r = 0; r < 4; ++r) oacc[mi][df][r] = 0.0f;
  float m_run[2][4], l_par[2][4];
  #pragma unroll
  for (int mi = 0; mi < 2; ++mi)
    #pragma unroll
    for (int r = 0; r < 4; ++r) { m_run[mi][r] = -1e30f; l_par[mi][r] = 0.0f; }

  // prologue: stage tile 0
  uint4 rk = *(const uint4*)(Ksrc);
  uint4 rf = *(const uint4*)(Kfsrc);
  uint4 rv = *(const uint4*)(Vsrc);
  *(uint4*)&K_s [0][srow][sw] = rk;
  *(uint4*)&Kf_s[0][srow][sw] = rf;
  *(uint4*)&Vt_s[0][srow][sw] = rv;
  __syncthreads();

  int cur = 0;
  for (int kt = 0; kt < 16; ++kt) {
    if (kt < 15) {
      const int ko = (kt + 1) * 4096;
      rk = *(const uint4*)(Ksrc  + ko);
      rf = *(const uint4*)(Kfsrc + ko);
      rv = *(const uint4*)(Vsrc  + (kt + 1) * 64);
    }

    // ---- S = Q K^T + Qf Kf^T (pre-scaled, log2 domain) ----
    f32x4 s[2][4];
    #pragma unroll
    for (int cf = 0; cf < 4; ++cf) {
      const int n = cf * 16 + ln;
      const int sx = n & 7;
      bf16x8 b0 = *(const bf16x8*)&K_s [cur][n][((0 + lg) ^ sx) * 8];
      bf16x8 b1 = *(const bf16x8*)&K_s [cur][n][((4 + lg) ^ sx) * 8];
      bf16x8 b2 = *(const bf16x8*)&Kf_s[cur][n][((0 + lg) ^ sx) * 8];
      bf16x8 b3 = *(const bf16x8*)&Kf_s[cur][n][((4 + lg) ^ sx) * 8];
      #pragma unroll
      for (int mi = 0; mi < 2; ++mi) {
        f32x4 a;
        #pragma unroll
        for (int r = 0; r < 4; ++r) a[r] = 0.0f;
        a = __builtin_amdgcn_mfma_f32_16x16x32_bf16(aq[mi][0], b0, a, 0, 0, 0);
        a = __builtin_amdgcn_mfma_f32_16x16x32_bf16(aq[mi][1], b1, a, 0, 0, 0);
        a = __builtin_amdgcn_mfma_f32_16x16x32_bf16(aq[mi][2], b2, a, 0, 0, 0);
        a = __builtin_amdgcn_mfma_f32_16x16x32_bf16(aq[mi][3], b3, a, 0, 0, 0);
        s[mi][cf] = a;
      }
    }

    // ---- defer-max online softmax ----
    float smax[2][4];
    bool viol = false;
    #pragma unroll
    for (int mi = 0; mi < 2; ++mi)
      #pragma unroll
      for (int r = 0; r < 4; ++r) {
        smax[mi][r] = fmaxf(fmaxf(s[mi][0][r], s[mi][1][r]),
                            fmaxf(s[mi][2][r], s[mi][3][r]));
        viol = viol || (smax[mi][r] > m_run[mi][r] + 11.0f);
      }
    if (__any(viol)) {
      #pragma unroll
      for (int off = 1; off < 16; off <<= 1)
        #pragma unroll
        for (int mi = 0; mi < 2; ++mi)
          #pragma unroll
          for (int r = 0; r < 4; ++r)
            smax[mi][r] = fmaxf(smax[mi][r], __shfl_xor(smax[mi][r], off, 64));
      #pragma unroll
      for (int mi = 0; mi < 2; ++mi)
        #pragma unroll
        for (int r = 0; r < 4; ++r) {
          const float mnew = fmaxf(m_run[mi][r], smax[mi][r]);
          const float corr = exp2f(m_run[mi][r] - mnew);
          m_run[mi][r] = mnew;
          l_par[mi][r] *= corr;
          #pragma unroll
          for (int df = 0; df < 4; ++df) oacc[mi][df][r] *= corr;
        }
    }
    #pragma unroll
    for (int mi = 0; mi < 2; ++mi)
      #pragma unroll
      for (int cf = 0; cf < 4; ++cf) {
        const int col = cf * 16 + ln;
        #pragma unroll
        for (int r = 0; r < 4; ++r) {
          const int rr = 4 * lg + r;
          const float p = exp2f(s[mi][cf][r] - m_run[mi][r]);
          l_par[mi][r] += p;
          P_s[wid][mi * 16 + rr][col ^ ((rr & 7) * 8)] =
              __builtin_bit_cast(u16, __float2bfloat16(p));
        }
      }

    // ---- O += P @ V ----
    #pragma unroll
    for (int kc = 0; kc < 2; ++kc) {
      const int kk = kc * 32 + lg * 8;
      bf16x8 ap0 = *(const bf16x8*)&P_s[wid][ln]     [kk ^ ((ln & 7) * 8)];
      bf16x8 ap1 = *(const bf16x8*)&P_s[wid][16 + ln][kk ^ ((ln & 7) * 8)];
      #pragma unroll
      for (int df = 0; df < 4; ++df) {
        const int n = df * 16 + ln;
        bf16x8 bv = *(const bf16x8*)&Vt_s[cur][n][((kc * 4 + lg) ^ (n & 7)) * 8];
        oacc[0][df] = __builtin_amdgcn_mfma_f32_16x16x32_bf16(ap0, bv, oacc[0][df], 0, 0, 0);
        oacc[1][df] = __builtin_amdgcn_mfma_f32_16x16x32_bf16(ap1, bv, oacc[1][df], 0, 0, 0);
      }
    }

    if (kt < 15) {
      *(uint4*)&K_s [cur ^ 1][srow][sw] = rk;
      *(uint4*)&Kf_s[cur ^ 1][srow][sw] = rf;
      *(uint4*)&Vt_s[cur ^ 1][srow][sw] = rv;
      __syncthreads();
      cur ^= 1;
    }
  }

  // epilogue: reduce l across 16 lanes; write unnormalized O + (m,l)
  #pragma unroll
  for (int off = 1; off < 16; off <<= 1)
    #pragma unroll
    for (int mi = 0; mi < 2; ++mi)
      #pragma unroll
      for (int r = 0; r < 4; ++r)
        l_par[mi][r] += __shfl_xor(l_par[mi][r], off, 64);

  #pragma unroll
  for (int mi = 0; mi < 2; ++mi)
    #pragma unroll
    for (int df = 0; df < 4; ++df)
      #pragma unroll
      for (int r = 0; r < 4; ++r) {
        const int row = r0 + mi * 16 + 4 * lg + r;
        const int col = df * 16 + ln;
        Op[(size_t)row * 64 + col] = f2bf(oacc[mi][df][r]);
      }
  if (ln == 0) {
    #pragma unroll
    for (int mi = 0; mi < 2; ++mi)
      #pragma unroll
      for (int r = 0; r < 4; ++r) {
        const int grow = bh * 2048 + r0 + mi * 16 + 4 * lg + r;
        mlbuf[split * 32768 + grow] = make_float2(m_run[mi][r], l_par[mi][r]);
      }
  }
}

// ---------------------------------------------------------------------------
// Combine the two KV-split partials: out = sum_i O_i*a_i / sum_i l_i*a_i.
// grid 1024 x 256, 8 cols/thread.
// ---------------------------------------------------------------------------
__global__ __launch_bounds__(256) void combine(
    const u16* __restrict__ opart, const float2* __restrict__ mlbuf,
    u16* __restrict__ att) {
  const int gid = blockIdx.x * 256 + threadIdx.x;
  const int row = gid >> 3, c8 = (gid & 7) * 8;
  const float2 ml1 = mlbuf[row];
  const float2 ml2 = mlbuf[32768 + row];
  const float mx = fmaxf(ml1.x, ml2.x);
  const float a1 = exp2f(ml1.x - mx), a2 = exp2f(ml2.x - mx);
  const float inv = 1.0f / (ml1.y * a1 + ml2.y * a2);
  const float w1 = a1 * inv, w2 = a2 * inv;
  uint4 o1 = *(const uint4*)&opart[(size_t)row * 64 + c8];
  uint4 o2 = *(const uint4*)&opart[2097152 + (size_t)row * 64 + c8];
  const u16* p1 = (const u16*)&o1;
  const u16* p2 = (const u16*)&o2;
  alignas(16) u16 ot[8];
  #pragma unroll
  for (int i = 0; i < 8; ++i)
    ot[i] = f2bf(bf2f(p1[i]) * w1 + bf2f(p2[i]) * w2);
  *(uint4*)&att[(size_t)row * 64 + c8] = *(const uint4*)ot;
}

// ---------------------------------------------------------------------------
extern "C" void kernel_launch(void* const* d_in, const int* in_sizes, int n_in,
                              void* d_out, int out_size, void* d_ws, size_t ws_size,
                              hipStream_t stream) {
  const float* x    = (const float*)d_in[0];
  const float* xk   = (const float*)d_in[1];
  const float* Wv   = (const float*)d_in[2];  const float* bv   = (const float*)d_in[3];
  const float* Wk   = (const float*)d_in[4];  const float* bk   = (const float*)d_in[5];
  const float* Wq   = (const float*)d_in[6];  const float* bq   = (const float*)d_in[7];
  const float* Wkf  = (const float*)d_in[8];  const float* bkf  = (const float*)d_in[9];
  const float* Wqf  = (const float*)d_in[10]; const float* bqf  = (const float*)d_in[11];
  const float* Wq2  = (const float*)d_in[12]; const float* bq2  = (const float*)d_in[13];
  const float* Wk2  = (const float*)d_in[14]; const float* bk2  = (const float*)d_in[15];
  const float* Wqf2 = (const float*)d_in[16]; const float* bqf2 = (const float*)d_in[17];
  const float* Wkf2 = (const float*)d_in[18]; const float* bkf2 = (const float*)d_in[19];
  const float* Wo   = (const float*)d_in[20]; const float* bo   = (const float*)d_in[21];

  u16* ws = (u16*)d_ws;
  u16* Wt = ws;                                   // 10 x 262144 u16 (5120x512)
  float* biasP = (float*)(ws + 2621440);          // 5120 f32
  u16* bufs = ws + 2621440 + 10240;
  const size_t BUF = 2097152;
  u16* v1  = bufs + 0 * BUF;   // stage-1 v; later att (combine output)
  u16* k1  = bufs + 1 * BUF;   // stage-1 k
  u16* q1  = bufs + 2 * BUF;   // stage-1 q; later vt (dead after stage-2)
  u16* kf1 = bufs + 3 * BUF;   // stage-1 kf; later O_part split 0
  u16* qf1 = bufs + 4 * BUF;   // stage-1 qf; later O_part split 1 (contig)
  u16* q2  = bufs + 5 * BUF;   // xb, then stage-2 q
  u16* k2  = bufs + 6 * BUF;   // xkb, then stage-2 k
  u16* qf2 = bufs + 7 * BUF;
  u16* kf2 = bufs + 8 * BUF;
  float2* mlbuf = (float2*)(bufs + 9 * BUF);      // 2 x 32768 float2

  cvt_bf16<<<dim3(1024, 2), 256, 0, stream>>>(x, xk, q2, k2);

  TPtrs tp;
  tp.p[0] = Wv;  tp.p[1] = Wk;  tp.p[2] = Wq;   tp.p[3] = Wkf;  tp.p[4] = Wqf;
  tp.p[5] = Wq2; tp.p[6] = Wk2; tp.p[7] = Wqf2; tp.p[8] = Wkf2; tp.p[9] = Wo;
  transposeW<<<dim3(8, 8, 10), 256, 0, stream>>>(tp, Wt);

  BPtrs bp;
  bp.p[0] = bv;  bp.p[1] = bk;  bp.p[2] = bq;   bp.p[3] = bkf;  bp.p[4] = bqf;
  bp.p[5] = bq2; bp.p[6] = bk2; bp.p[7] = bqf2; bp.p[8] = bkf2; bp.p[9] = bo;
  biasPack<<<dim3(10), 512, 0, stream>>>(bp, biasP);

  // stage-1 fused (x and xk in one launch): v,k,q from x; kf,qf from xk
  GemmBatch g1 = {};
  g1.A[0] = q2;  g1.Ax = k2;  g1.xsplit = 12;
  g1.out[0] = v1; g1.out[1] = k1; g1.out[2] = q1; g1.out[3] = kf1; g1.out[4] = qf1;
  g1.wrow0 = 0; g1.zstride = 0;
  gemm3<u16><<<dim3(20, 32, 1), 256, 0, stream>>>(g1, Wt, biasP);

  // stage-2 batched: {q1,k1,qf1,kf1} @ {Wq2,Wk2,Wqf2,Wkf2} -> {q2,k2,qf2,kf2}
  GemmBatch g3 = {};
  g3.A[0] = q1; g3.A[1] = k1; g3.A[2] = qf1; g3.A[3] = kf1;
  g3.Ax = q1; g3.xsplit = 100;
  g3.out[0] = q2; g3.out[1] = k2; g3.out[2] = qf2; g3.out[3] = kf2;
  g3.wrow0 = 2560; g3.zstride = 512;
  gemm3<u16><<<dim3(4, 32, 4), 256, 0, stream>>>(g3, Wt, biasP);

  // V transpose per head-block (v1 -> q1; q1 dead after stage-2)
  transposeV<<<dim3(32, 16), 256, 0, stream>>>(v1, q1);

  // attention: 256 blocks x 512 threads (1/CU, 8 waves), KV-split x2
  attn5<<<dim3(256), 512, 0, stream>>>(q2, k2, qf2, kf2, q1, kf1, mlbuf);

  // combine partials -> att (v1)
  combine<<<dim3(1024), 256, 0, stream>>>(kf1, mlbuf, v1);

  // final: att @ Wo + bo -> d_out (fp32)
  GemmBatch g4 = {};
  g4.A[0] = v1; g4.Ax = v1; g4.xsplit = 100;
  g4.out[0] = d_out;
  g4.wrow0 = 4608; g4.zstride = 0;
  gemm3<float><<<dim3(4, 32, 1), 256, 0, stream>>>(g4, Wt, biasP);
}

// Round 7
// 119.374 us; speedup vs baseline: 1.1878x; 1.0016x over previous
//
#include <hip/hip_runtime.h>
#include <hip/hip_bf16.h>

typedef unsigned short u16;
typedef unsigned int   u32;
typedef __attribute__((ext_vector_type(8))) short bf16x8;
typedef __attribute__((ext_vector_type(4))) float f32x4;

#define SCALE 0.08838834764831845f                 // 1/sqrt(2*64)
#define SCLOG 0.12752040542575836f                 // SCALE * log2(e)

__device__ inline u16 f2bf(float f) {
  u32 u = __builtin_bit_cast(u32, f);
  u = (u + 0x7FFFu + ((u >> 16) & 1u)) >> 16;      // RNE
  return (u16)u;
}
__device__ inline float bf2f(u16 b) {
  u32 u = (u32)b << 16;
  return __builtin_bit_cast(float, u);
}

// ---------------------------------------------------------------------------
// fp32 -> bf16 bulk convert (x and x_knowledge). grid (1024, 2), 8 elems/thr.
// ---------------------------------------------------------------------------
__global__ __launch_bounds__(256) void cvt_bf16(const float* __restrict__ a,
                                                const float* __restrict__ b,
                                                u16* __restrict__ oa,
                                                u16* __restrict__ ob) {
  const float* in = blockIdx.y ? b : a;
  u16* out = blockIdx.y ? ob : oa;
  const int i = (blockIdx.x * 256 + threadIdx.x) * 8;
  float4 f0 = *(const float4*)(in + i);
  float4 f1 = *(const float4*)(in + i + 4);
  alignas(16) u16 t[8] = {f2bf(f0.x), f2bf(f0.y), f2bf(f0.z), f2bf(f0.w),
                          f2bf(f1.x), f2bf(f1.y), f2bf(f1.z), f2bf(f1.w)};
  *(uint4*)(out + i) = *(const uint4*)t;
}

// ---------------------------------------------------------------------------
// Weight transpose Wt[z][n][k] = W[z][k][n] (fp32->bf16); slots 5,7 scaled
// by SCALE*log2e (folds attn scale + exp->exp2 into Q,Qf projections).
// ---------------------------------------------------------------------------
struct TPtrs { const float* p[10]; };

__global__ __launch_bounds__(256) void transposeW(TPtrs ptrs, u16* __restrict__ out) {
  __shared__ u16 ts[64][65];
  const float sc = (blockIdx.z == 5 || blockIdx.z == 7) ? SCLOG : 1.0f;
  const float* in = ptrs.p[blockIdx.z];
  u16* o = out + (size_t)blockIdx.z * 262144;
  const int t = threadIdx.x;
  const int k0 = blockIdx.y * 64, n0 = blockIdx.x * 64;
  for (int pp = 0; pp < 16; ++pp) {
    int id = t + 256 * pp; int r = id >> 6, c = id & 63;
    ts[r][c] = f2bf(in[(size_t)(k0 + r) * 512 + n0 + c] * sc);
  }
  __syncthreads();
  for (int pp = 0; pp < 16; ++pp) {
    int id = t + 256 * pp; int r = id >> 6, c = id & 63;
    o[(size_t)(n0 + r) * 512 + k0 + c] = ts[c][r];
  }
}

struct BPtrs { const float* p[10]; };

__global__ __launch_bounds__(512) void biasPack(BPtrs bp, float* __restrict__ out) {
  const int z = blockIdx.x, n = threadIdx.x;
  const float sc = (z == 5 || z == 7) ? SCLOG : 1.0f;
  out[z * 512 + n] = bp.p[z][n] * sc;
}

// ---------------------------------------------------------------------------
// Per-head V transpose: v1 (2048,64) -> vt (64,2048) per head-block.
// grid (32,16).
// ---------------------------------------------------------------------------
__global__ __launch_bounds__(256) void transposeV(const u16* __restrict__ v1,
                                                  u16* __restrict__ vt) {
  __shared__ u16 ts[64][65];
  const size_t base = (size_t)blockIdx.y * 131072;
  const u16* in = v1 + base;
  u16* out = vt + base;
  const int l0 = blockIdx.x * 64;
  const int t = threadIdx.x;
  const int r = t >> 3, c8 = (t & 7) * 8;
  for (int pp = 0; pp < 2; ++pp) {
    int rr = r + pp * 32;
    *(uint4*)&ts[rr][c8] = *(const uint4*)&in[(size_t)(l0 + rr) * 64 + c8];
  }
  __syncthreads();
  for (int pp = 0; pp < 2; ++pp) {
    int d = r + pp * 32;
    alignas(16) u16 tmp[8];
    #pragma unroll
    for (int i = 0; i < 8; ++i) tmp[i] = ts[c8 + i][d];
    *(uint4*)&out[(size_t)d * 2048 + l0 + c8] = *(const uint4*)tmp;
  }
}

// ---------------------------------------------------------------------------
// GEMM: 128x128 tile, BK=64, 4 waves (2x2) of 64x64. 2-phase dbuf, reg-staged,
// XOR-swizzled LDS. Wt is one (5120 x 512) matrix; wrow = wrow0+z*zstride+
// blockIdx.x*128. A switches to Ax at tile xsplit (stage-1 fusion).
// ---------------------------------------------------------------------------
struct GemmBatch {
  const u16* A[4];
  const u16* Ax;
  int xsplit;
  void* out[5];        // indexed by (wrow>>9) - (wrow0>>9)
  int wrow0, zstride;
};

template <typename TOUT>
__global__ __launch_bounds__(256, 2) void gemm3(GemmBatch gb,
    const u16* __restrict__ Wt, const float* __restrict__ biasP) {
  const int tx = blockIdx.x, z = blockIdx.z;
  const u16* A = (tx < gb.xsplit) ? gb.A[z] : gb.Ax;
  const int wrow = gb.wrow0 + z * gb.zstride + tx * 128;
  const int m0 = blockIdx.y * 128;
  const u16* B = Wt + (size_t)wrow * 512;
  const float* bias = biasP + wrow;

  const int t = threadIdx.x, wid = t >> 6, lane = t & 63;
  const int lg = lane >> 4, ln = lane & 15;
  const int wr = wid >> 1, wc = wid & 1;

  __shared__ u16 As[2][128][64];
  __shared__ u16 Bs[2][128][64];

  const int srow = t >> 3, sch = t & 7;
  const int sw = (sch ^ (srow & 7)) * 8;
  const u16* Asrc = A + (size_t)(m0 + srow) * 512 + sch * 8;
  const u16* Bsrc = B + (size_t)srow * 512 + sch * 8;

  uint4 ra[4], rb[4];
  #pragma unroll
  for (int p = 0; p < 4; ++p) {
    ra[p] = *(const uint4*)(Asrc + p * 32 * 512);
    rb[p] = *(const uint4*)(Bsrc + p * 32 * 512);
  }
  #pragma unroll
  for (int p = 0; p < 4; ++p) {
    *(uint4*)&As[0][srow + 32 * p][sw] = ra[p];
    *(uint4*)&Bs[0][srow + 32 * p][sw] = rb[p];
  }
  __syncthreads();

  f32x4 acc[4][4];
  #pragma unroll
  for (int i = 0; i < 4; ++i)
    #pragma unroll
    for (int j = 0; j < 4; ++j)
      #pragma unroll
      for (int r = 0; r < 4; ++r) acc[i][j][r] = 0.0f;

  int cur = 0;
  for (int kt = 0; kt < 8; ++kt) {
    if (kt < 7) {
      const int ko = (kt + 1) * 64;
      #pragma unroll
      for (int p = 0; p < 4; ++p) {
        ra[p] = *(const uint4*)(Asrc + ko + p * 32 * 512);
        rb[p] = *(const uint4*)(Bsrc + ko + p * 32 * 512);
      }
    }
    #pragma unroll
    for (int ck = 0; ck < 2; ++ck) {
      bf16x8 af[4], bfr[4];
      #pragma unroll
      for (int mi = 0; mi < 4; ++mi) {
        const int r = wr * 64 + mi * 16 + ln;
        af[mi] = *(const bf16x8*)&As[cur][r][((ck * 4 + lg) ^ (r & 7)) * 8];
      }
      #pragma unroll
      for (int ni = 0; ni < 4; ++ni) {
        const int r = wc * 64 + ni * 16 + ln;
        bfr[ni] = *(const bf16x8*)&Bs[cur][r][((ck * 4 + lg) ^ (r & 7)) * 8];
      }
      #pragma unroll
      for (int mi = 0; mi < 4; ++mi)
        #pragma unroll
        for (int ni = 0; ni < 4; ++ni)
          acc[mi][ni] = __builtin_amdgcn_mfma_f32_16x16x32_bf16(
              af[mi], bfr[ni], acc[mi][ni], 0, 0, 0);
    }
    if (kt < 7) {
      #pragma unroll
      for (int p = 0; p < 4; ++p) {
        *(uint4*)&As[cur ^ 1][srow + 32 * p][sw] = ra[p];
        *(uint4*)&Bs[cur ^ 1][srow + 32 * p][sw] = rb[p];
      }
      __syncthreads();
      cur ^= 1;
    }
  }

  TOUT* C = (TOUT*)gb.out[(wrow >> 9) - (gb.wrow0 >> 9)];
  const int nbase = wrow & 511;
  #pragma unroll
  for (int ni = 0; ni < 4; ++ni) {
    const int colw = wc * 64 + ni * 16 + ln;
    const float bv = bias[colw];
    const int col = nbase + colw;
    #pragma unroll
    for (int mi = 0; mi < 4; ++mi)
      #pragma unroll
      for (int r = 0; r < 4; ++r) {
        const int row = m0 + wr * 64 + mi * 16 + 4 * lg + r;
        const float val = acc[mi][ni][r] + bv;
        if constexpr (sizeof(TOUT) == 4) C[(size_t)row * 512 + col] = val;
        else                             C[(size_t)row * 512 + col] = f2bf(val);
      }
  }
}

// ---------------------------------------------------------------------------
// Flash attention: 512 threads = 8 waves x 32 Q-rows (QBLK=256), KVBLK=64,
// KV-split x2. grid 256 = exactly 1 block/CU -> 8 waves/CU = 2/SIMD
// deterministic (intra-block TLP; no inter-block LDS co-residency gamble).
// K/Kf/Vt double-buffered (48 KiB) + per-wave P_s (32 KiB) = 80 KiB LDS.
// Defer-max (THR=11, log2 domain), Q pre-scaled by SCALE*log2e.
// Writes unnormalized O (bf16) + (m,l) per row; combine kernel merges splits.
// ---------------------------------------------------------------------------
__global__ __launch_bounds__(512) void attn5(
    const u16* __restrict__ q2, const u16* __restrict__ k2,
    const u16* __restrict__ qf2, const u16* __restrict__ kf2,
    const u16* __restrict__ vtg, u16* __restrict__ opart,
    float2* __restrict__ mlbuf) {
  const int id = blockIdx.x;
  const int nid = (id & 7) * 32 + (id >> 3);   // XCD-bijective: 2 heads/XCD
  const int split = nid & 1;
  const int qt = (nid >> 1) & 7;
  const int bh = nid >> 4;
  const size_t base = (size_t)bh * 131072;
  const int kv0 = split * 1024;

  const u16* Q  = q2  + base;
  const u16* Qf = qf2 + base;
  u16* Op = opart + (size_t)split * 2097152 + base;

  const int t = threadIdx.x, wid = t >> 6, lane = t & 63;
  const int lg = lane >> 4, ln = lane & 15;
  const int r0 = qt * 256 + wid * 32;          // this wave's 32 Q rows (local)

  __shared__ u16 K_s [2][64][64];
  __shared__ u16 Kf_s[2][64][64];
  __shared__ u16 Vt_s[2][64][64];
  __shared__ u16 P_s [8][32][64];

  const int srow = t >> 3, sch = t & 7;        // 64 rows x 8 chunks, 1 uint4/thr
  const int sw = (sch ^ (srow & 7)) * 8;
  const u16* Ksrc  = k2  + base + (size_t)(kv0 + srow) * 64 + sch * 8;
  const u16* Kfsrc = kf2 + base + (size_t)(kv0 + srow) * 64 + sch * 8;
  const u16* Vsrc  = vtg + base + (size_t)srow * 2048 + kv0 + sch * 8;

  bf16x8 aq[2][4];
  #pragma unroll
  for (int mi = 0; mi < 2; ++mi) {
    const int row = r0 + mi * 16 + ln;
    aq[mi][0] = *(const bf16x8*)&Q [row * 64 +      lg * 8];
    aq[mi][1] = *(const bf16x8*)&Q [row * 64 + 32 + lg * 8];
    aq[mi][2] = *(const bf16x8*)&Qf[row * 64 +      lg * 8];
    aq[mi][3] = *(const bf16x8*)&Qf[row * 64 + 32 + lg * 8];
  }

  f32x4 oacc[2][4];
  #pragma unroll
  for (int mi = 0; mi < 2; ++mi)
    #pragma unroll
    for (int df = 0; df < 4; ++df)
      #pragma unroll
      for (int r = 0; r < 4; ++r) oacc[mi][df][r] = 0.0f;
  float m_run[2][4], l_par[2][4];
  #pragma unroll
  for (int mi = 0; mi < 2; ++mi)
    #pragma unroll
    for (int r = 0; r < 4; ++r) { m_run[mi][r] = -1e30f; l_par[mi][r] = 0.0f; }

  // prologue: stage tile 0
  uint4 rk = *(const uint4*)(Ksrc);
  uint4 rf = *(const uint4*)(Kfsrc);
  uint4 rv = *(const uint4*)(Vsrc);
  *(uint4*)&K_s [0][srow][sw] = rk;
  *(uint4*)&Kf_s[0][srow][sw] = rf;
  *(uint4*)&Vt_s[0][srow][sw] = rv;
  __syncthreads();

  int cur = 0;
  for (int kt = 0; kt < 16; ++kt) {
    if (kt < 15) {
      const int ko = (kt + 1) * 4096;
      rk = *(const uint4*)(Ksrc  + ko);
      rf = *(const uint4*)(Kfsrc + ko);
      rv = *(const uint4*)(Vsrc  + (kt + 1) * 64);
    }

    // ---- S = Q K^T + Qf Kf^T (pre-scaled, log2 domain) ----
    f32x4 s[2][4];
    #pragma unroll
    for (int cf = 0; cf < 4; ++cf) {
      const int n = cf * 16 + ln;
      const int sx = n & 7;
      bf16x8 b0 = *(const bf16x8*)&K_s [cur][n][((0 + lg) ^ sx) * 8];
      bf16x8 b1 = *(const bf16x8*)&K_s [cur][n][((4 + lg) ^ sx) * 8];
      bf16x8 b2 = *(const bf16x8*)&Kf_s[cur][n][((0 + lg) ^ sx) * 8];
      bf16x8 b3 = *(const bf16x8*)&Kf_s[cur][n][((4 + lg) ^ sx) * 8];
      #pragma unroll
      for (int mi = 0; mi < 2; ++mi) {
        f32x4 a;
        #pragma unroll
        for (int r = 0; r < 4; ++r) a[r] = 0.0f;
        a = __builtin_amdgcn_mfma_f32_16x16x32_bf16(aq[mi][0], b0, a, 0, 0, 0);
        a = __builtin_amdgcn_mfma_f32_16x16x32_bf16(aq[mi][1], b1, a, 0, 0, 0);
        a = __builtin_amdgcn_mfma_f32_16x16x32_bf16(aq[mi][2], b2, a, 0, 0, 0);
        a = __builtin_amdgcn_mfma_f32_16x16x32_bf16(aq[mi][3], b3, a, 0, 0, 0);
        s[mi][cf] = a;
      }
    }

    // ---- defer-max online softmax ----
    float smax[2][4];
    bool viol = false;
    #pragma unroll
    for (int mi = 0; mi < 2; ++mi)
      #pragma unroll
      for (int r = 0; r < 4; ++r) {
        smax[mi][r] = fmaxf(fmaxf(s[mi][0][r], s[mi][1][r]),
                            fmaxf(s[mi][2][r], s[mi][3][r]));
        viol = viol || (smax[mi][r] > m_run[mi][r] + 11.0f);
      }
    if (__any(viol)) {
      #pragma unroll
      for (int off = 1; off < 16; off <<= 1)
        #pragma unroll
        for (int mi = 0; mi < 2; ++mi)
          #pragma unroll
          for (int r = 0; r < 4; ++r)
            smax[mi][r] = fmaxf(smax[mi][r], __shfl_xor(smax[mi][r], off, 64));
      #pragma unroll
      for (int mi = 0; mi < 2; ++mi)
        #pragma unroll
        for (int r = 0; r < 4; ++r) {
          const float mnew = fmaxf(m_run[mi][r], smax[mi][r]);
          const float corr = exp2f(m_run[mi][r] - mnew);
          m_run[mi][r] = mnew;
          l_par[mi][r] *= corr;
          #pragma unroll
          for (int df = 0; df < 4; ++df) oacc[mi][df][r] *= corr;
        }
    }
    #pragma unroll
    for (int mi = 0; mi < 2; ++mi)
      #pragma unroll
      for (int cf = 0; cf < 4; ++cf) {
        const int col = cf * 16 + ln;
        #pragma unroll
        for (int r = 0; r < 4; ++r) {
          const int rr = 4 * lg + r;
          const float p = exp2f(s[mi][cf][r] - m_run[mi][r]);
          l_par[mi][r] += p;
          P_s[wid][mi * 16 + rr][col ^ ((rr & 7) * 8)] =
              __builtin_bit_cast(u16, __float2bfloat16(p));
        }
      }

    // ---- O += P @ V ----
    #pragma unroll
    for (int kc = 0; kc < 2; ++kc) {
      const int kk = kc * 32 + lg * 8;
      bf16x8 ap0 = *(const bf16x8*)&P_s[wid][ln]     [kk ^ ((ln & 7) * 8)];
      bf16x8 ap1 = *(const bf16x8*)&P_s[wid][16 + ln][kk ^ ((ln & 7) * 8)];
      #pragma unroll
      for (int df = 0; df < 4; ++df) {
        const int n = df * 16 + ln;
        bf16x8 bv = *(const bf16x8*)&Vt_s[cur][n][((kc * 4 + lg) ^ (n & 7)) * 8];
        oacc[0][df] = __builtin_amdgcn_mfma_f32_16x16x32_bf16(ap0, bv, oacc[0][df], 0, 0, 0);
        oacc[1][df] = __builtin_amdgcn_mfma_f32_16x16x32_bf16(ap1, bv, oacc[1][df], 0, 0, 0);
      }
    }

    if (kt < 15) {
      *(uint4*)&K_s [cur ^ 1][srow][sw] = rk;
      *(uint4*)&Kf_s[cur ^ 1][srow][sw] = rf;
      *(uint4*)&Vt_s[cur ^ 1][srow][sw] = rv;
      __syncthreads();
      cur ^= 1;
    }
  }

  // epilogue: reduce l across 16 lanes; write unnormalized O + (m,l)
  #pragma unroll
  for (int off = 1; off < 16; off <<= 1)
    #pragma unroll
    for (int mi = 0; mi < 2; ++mi)
      #pragma unroll
      for (int r = 0; r < 4; ++r)
        l_par[mi][r] += __shfl_xor(l_par[mi][r], off, 64);

  #pragma unroll
  for (int mi = 0; mi < 2; ++mi)
    #pragma unroll
    for (int df = 0; df < 4; ++df)
      #pragma unroll
      for (int r = 0; r < 4; ++r) {
        const int row = r0 + mi * 16 + 4 * lg + r;
        const int col = df * 16 + ln;
        Op[(size_t)row * 64 + col] = f2bf(oacc[mi][df][r]);
      }
  if (ln == 0) {
    #pragma unroll
    for (int mi = 0; mi < 2; ++mi)
      #pragma unroll
      for (int r = 0; r < 4; ++r) {
        const int grow = bh * 2048 + r0 + mi * 16 + 4 * lg + r;
        mlbuf[split * 32768 + grow] = make_float2(m_run[mi][r], l_par[mi][r]);
      }
  }
}

// ---------------------------------------------------------------------------
// Combine the two KV-split partials: out = sum_i O_i*a_i / sum_i l_i*a_i.
// grid 1024 x 256, 8 cols/thread.
// ---------------------------------------------------------------------------
__global__ __launch_bounds__(256) void combine(
    const u16* __restrict__ opart, const float2* __restrict__ mlbuf,
    u16* __restrict__ att) {
  const int gid = blockIdx.x * 256 + threadIdx.x;
  const int row = gid >> 3, c8 = (gid & 7) * 8;
  const float2 ml1 = mlbuf[row];
  const float2 ml2 = mlbuf[32768 + row];
  const float mx = fmaxf(ml1.x, ml2.x);
  const float a1 = exp2f(ml1.x - mx), a2 = exp2f(ml2.x - mx);
  const float inv = 1.0f / (ml1.y * a1 + ml2.y * a2);
  const float w1 = a1 * inv, w2 = a2 * inv;
  uint4 o1 = *(const uint4*)&opart[(size_t)row * 64 + c8];
  uint4 o2 = *(const uint4*)&opart[2097152 + (size_t)row * 64 + c8];
  const u16* p1 = (const u16*)&o1;
  const u16* p2 = (const u16*)&o2;
  alignas(16) u16 ot[8];
  #pragma unroll
  for (int i = 0; i < 8; ++i)
    ot[i] = f2bf(bf2f(p1[i]) * w1 + bf2f(p2[i]) * w2);
  *(uint4*)&att[(size_t)row * 64 + c8] = *(const uint4*)ot;
}

// ---------------------------------------------------------------------------
extern "C" void kernel_launch(void* const* d_in, const int* in_sizes, int n_in,
                              void* d_out, int out_size, void* d_ws, size_t ws_size,
                              hipStream_t stream) {
  const float* x    = (const float*)d_in[0];
  const float* xk   = (const float*)d_in[1];
  const float* Wv   = (const float*)d_in[2];  const float* bv   = (const float*)d_in[3];
  const float* Wk   = (const float*)d_in[4];  const float* bk   = (const float*)d_in[5];
  const float* Wq   = (const float*)d_in[6];  const float* bq   = (const float*)d_in[7];
  const float* Wkf  = (const float*)d_in[8];  const float* bkf  = (const float*)d_in[9];
  const float* Wqf  = (const float*)d_in[10]; const float* bqf  = (const float*)d_in[11];
  const float* Wq2  = (const float*)d_in[12]; const float* bq2  = (const float*)d_in[13];
  const float* Wk2  = (const float*)d_in[14]; const float* bk2  = (const float*)d_in[15];
  const float* Wqf2 = (const float*)d_in[16]; const float* bqf2 = (const float*)d_in[17];
  const float* Wkf2 = (const float*)d_in[18]; const float* bkf2 = (const float*)d_in[19];
  const float* Wo   = (const float*)d_in[20]; const float* bo   = (const float*)d_in[21];

  u16* ws = (u16*)d_ws;
  u16* Wt = ws;                                   // 10 x 262144 u16 (5120x512)
  float* biasP = (float*)(ws + 2621440);          // 5120 f32
  u16* bufs = ws + 2621440 + 10240;
  const size_t BUF = 2097152;
  u16* v1  = bufs + 0 * BUF;   // stage-1 v; later att (combine output)
  u16* k1  = bufs + 1 * BUF;   // stage-1 k
  u16* q1  = bufs + 2 * BUF;   // stage-1 q; later vt (dead after stage-2)
  u16* kf1 = bufs + 3 * BUF;   // stage-1 kf; later O_part split 0
  u16* qf1 = bufs + 4 * BUF;   // stage-1 qf; later O_part split 1 (contig)
  u16* q2  = bufs + 5 * BUF;   // xb, then stage-2 q
  u16* k2  = bufs + 6 * BUF;   // xkb, then stage-2 k
  u16* qf2 = bufs + 7 * BUF;
  u16* kf2 = bufs + 8 * BUF;
  float2* mlbuf = (float2*)(bufs + 9 * BUF);      // 2 x 32768 float2

  cvt_bf16<<<dim3(1024, 2), 256, 0, stream>>>(x, xk, q2, k2);

  TPtrs tp;
  tp.p[0] = Wv;  tp.p[1] = Wk;  tp.p[2] = Wq;   tp.p[3] = Wkf;  tp.p[4] = Wqf;
  tp.p[5] = Wq2; tp.p[6] = Wk2; tp.p[7] = Wqf2; tp.p[8] = Wkf2; tp.p[9] = Wo;
  transposeW<<<dim3(8, 8, 10), 256, 0, stream>>>(tp, Wt);

  BPtrs bp;
  bp.p[0] = bv;  bp.p[1] = bk;  bp.p[2] = bq;   bp.p[3] = bkf;  bp.p[4] = bqf;
  bp.p[5] = bq2; bp.p[6] = bk2; bp.p[7] = bqf2; bp.p[8] = bkf2; bp.p[9] = bo;
  biasPack<<<dim3(10), 512, 0, stream>>>(bp, biasP);

  // stage-1 fused (x and xk in one launch): v,k,q from x; kf,qf from xk
  GemmBatch g1 = {};
  g1.A[0] = q2;  g1.Ax = k2;  g1.xsplit = 12;
  g1.out[0] = v1; g1.out[1] = k1; g1.out[2] = q1; g1.out[3] = kf1; g1.out[4] = qf1;
  g1.wrow0 = 0; g1.zstride = 0;
  gemm3<u16><<<dim3(20, 32, 1), 256, 0, stream>>>(g1, Wt, biasP);

  // stage-2 batched: {q1,k1,qf1,kf1} @ {Wq2,Wk2,Wqf2,Wkf2} -> {q2,k2,qf2,kf2}
  GemmBatch g3 = {};
  g3.A[0] = q1; g3.A[1] = k1; g3.A[2] = qf1; g3.A[3] = kf1;
  g3.Ax = q1; g3.xsplit = 100;
  g3.out[0] = q2; g3.out[1] = k2; g3.out[2] = qf2; g3.out[3] = kf2;
  g3.wrow0 = 2560; g3.zstride = 512;
  gemm3<u16><<<dim3(4, 32, 4), 256, 0, stream>>>(g3, Wt, biasP);

  // V transpose per head-block (v1 -> q1; q1 dead after stage-2)
  transposeV<<<dim3(32, 16), 256, 0, stream>>>(v1, q1);

  // attention: 256 blocks x 512 threads (1/CU, 8 waves), KV-split x2
  attn5<<<dim3(256), 512, 0, stream>>>(q2, k2, qf2, kf2, q1, kf1, mlbuf);

  // combine partials -> att (v1)
  combine<<<dim3(1024), 256, 0, stream>>>(kf1, mlbuf, v1);

  // final: att @ Wo + bo -> d_out (fp32)
  GemmBatch g4 = {};
  g4.A[0] = v1; g4.Ax = v1; g4.xsplit = 100;
  g4.out[0] = d_out;
  g4.wrow0 = 4608; g4.zstride = 0;
  gemm3<float><<<dim3(4, 32, 1), 256, 0, stream>>>(g4, Wt, biasP);
}

// Round 8
// 118.943 us; speedup vs baseline: 1.1921x; 1.0036x over previous
//
#include <hip/hip_runtime.h>
#include <hip/hip_bf16.h>

typedef unsigned short u16;
typedef unsigned int   u32;
typedef __attribute__((ext_vector_type(8))) short bf16x8;
typedef __attribute__((ext_vector_type(4))) float f32x4;

#define SCALE 0.08838834764831845f                 // 1/sqrt(2*64)
#define SCLOG 0.12752040542575836f                 // SCALE * log2(e)

__device__ inline u16 f2bf(float f) {
  u32 u = __builtin_bit_cast(u32, f);
  u = (u + 0x7FFFu + ((u >> 16) & 1u)) >> 16;      // RNE
  return (u16)u;
}
__device__ inline float bf2f(u16 b) {
  u32 u = (u32)b << 16;
  return __builtin_bit_cast(float, u);
}

// ---------------------------------------------------------------------------
// fp32 -> bf16 bulk convert (x and x_knowledge). grid (1024, 2), 8 elems/thr.
// ---------------------------------------------------------------------------
__global__ __launch_bounds__(256) void cvt_bf16(const float* __restrict__ a,
                                                const float* __restrict__ b,
                                                u16* __restrict__ oa,
                                                u16* __restrict__ ob) {
  const float* in = blockIdx.y ? b : a;
  u16* out = blockIdx.y ? ob : oa;
  const int i = (blockIdx.x * 256 + threadIdx.x) * 8;
  float4 f0 = *(const float4*)(in + i);
  float4 f1 = *(const float4*)(in + i + 4);
  alignas(16) u16 t[8] = {f2bf(f0.x), f2bf(f0.y), f2bf(f0.z), f2bf(f0.w),
                          f2bf(f1.x), f2bf(f1.y), f2bf(f1.z), f2bf(f1.w)};
  *(uint4*)(out + i) = *(const uint4*)t;
}

// ---------------------------------------------------------------------------
// Weight transpose Wt[z][n][k] = W[z][k][n] (fp32->bf16); slots 5,7 scaled
// by SCALE*log2e (folds attn scale + exp->exp2 into Q,Qf projections).
// ---------------------------------------------------------------------------
struct TPtrs { const float* p[10]; };

__global__ __launch_bounds__(256) void transposeW(TPtrs ptrs, u16* __restrict__ out) {
  __shared__ u16 ts[64][65];
  const float sc = (blockIdx.z == 5 || blockIdx.z == 7) ? SCLOG : 1.0f;
  const float* in = ptrs.p[blockIdx.z];
  u16* o = out + (size_t)blockIdx.z * 262144;
  const int t = threadIdx.x;
  const int k0 = blockIdx.y * 64, n0 = blockIdx.x * 64;
  for (int pp = 0; pp < 16; ++pp) {
    int id = t + 256 * pp; int r = id >> 6, c = id & 63;
    ts[r][c] = f2bf(in[(size_t)(k0 + r) * 512 + n0 + c] * sc);
  }
  __syncthreads();
  for (int pp = 0; pp < 16; ++pp) {
    int id = t + 256 * pp; int r = id >> 6, c = id & 63;
    o[(size_t)(n0 + r) * 512 + k0 + c] = ts[c][r];
  }
}

struct BPtrs { const float* p[10]; };

__global__ __launch_bounds__(512) void biasPack(BPtrs bp, float* __restrict__ out) {
  const int z = blockIdx.x, n = threadIdx.x;
  const float sc = (z == 5 || z == 7) ? SCLOG : 1.0f;
  out[z * 512 + n] = bp.p[z][n] * sc;
}

// ---------------------------------------------------------------------------
// Per-head V transpose: v1 (2048,64) -> vt (64,2048) per head-block.
// grid (32,16).
// ---------------------------------------------------------------------------
__global__ __launch_bounds__(256) void transposeV(const u16* __restrict__ v1,
                                                  u16* __restrict__ vt) {
  __shared__ u16 ts[64][65];
  const size_t base = (size_t)blockIdx.y * 131072;
  const u16* in = v1 + base;
  u16* out = vt + base;
  const int l0 = blockIdx.x * 64;
  const int t = threadIdx.x;
  const int r = t >> 3, c8 = (t & 7) * 8;
  for (int pp = 0; pp < 2; ++pp) {
    int rr = r + pp * 32;
    *(uint4*)&ts[rr][c8] = *(const uint4*)&in[(size_t)(l0 + rr) * 64 + c8];
  }
  __syncthreads();
  for (int pp = 0; pp < 2; ++pp) {
    int d = r + pp * 32;
    alignas(16) u16 tmp[8];
    #pragma unroll
    for (int i = 0; i < 8; ++i) tmp[i] = ts[c8 + i][d];
    *(uint4*)&out[(size_t)d * 2048 + l0 + c8] = *(const uint4*)tmp;
  }
}

// ---------------------------------------------------------------------------
// GEMM: 128x128 tile, BK=64, 4 waves (2x2) of 64x64. 2-phase dbuf, reg-staged,
// XOR-swizzled LDS. Wt is one (5120 x 512) matrix; wrow = wrow0+z*zstride+
// blockIdx.x*128. A switches to Ax at tile xsplit (stage-1 fusion).
// ---------------------------------------------------------------------------
struct GemmBatch {
  const u16* A[4];
  const u16* Ax;
  int xsplit;
  void* out[5];        // indexed by (wrow>>9) - (wrow0>>9)
  int wrow0, zstride;
};

template <typename TOUT>
__global__ __launch_bounds__(256, 2) void gemm3(GemmBatch gb,
    const u16* __restrict__ Wt, const float* __restrict__ biasP) {
  const int tx = blockIdx.x, z = blockIdx.z;
  const u16* A = (tx < gb.xsplit) ? gb.A[z] : gb.Ax;
  const int wrow = gb.wrow0 + z * gb.zstride + tx * 128;
  const int m0 = blockIdx.y * 128;
  const u16* B = Wt + (size_t)wrow * 512;
  const float* bias = biasP + wrow;

  const int t = threadIdx.x, wid = t >> 6, lane = t & 63;
  const int lg = lane >> 4, ln = lane & 15;
  const int wr = wid >> 1, wc = wid & 1;

  __shared__ u16 As[2][128][64];
  __shared__ u16 Bs[2][128][64];

  const int srow = t >> 3, sch = t & 7;
  const int sw = (sch ^ (srow & 7)) * 8;
  const u16* Asrc = A + (size_t)(m0 + srow) * 512 + sch * 8;
  const u16* Bsrc = B + (size_t)srow * 512 + sch * 8;

  uint4 ra[4], rb[4];
  #pragma unroll
  for (int p = 0; p < 4; ++p) {
    ra[p] = *(const uint4*)(Asrc + p * 32 * 512);
    rb[p] = *(const uint4*)(Bsrc + p * 32 * 512);
  }
  #pragma unroll
  for (int p = 0; p < 4; ++p) {
    *(uint4*)&As[0][srow + 32 * p][sw] = ra[p];
    *(uint4*)&Bs[0][srow + 32 * p][sw] = rb[p];
  }
  __syncthreads();

  f32x4 acc[4][4];
  #pragma unroll
  for (int i = 0; i < 4; ++i)
    #pragma unroll
    for (int j = 0; j < 4; ++j)
      #pragma unroll
      for (int r = 0; r < 4; ++r) acc[i][j][r] = 0.0f;

  int cur = 0;
  for (int kt = 0; kt < 8; ++kt) {
    if (kt < 7) {
      const int ko = (kt + 1) * 64;
      #pragma unroll
      for (int p = 0; p < 4; ++p) {
        ra[p] = *(const uint4*)(Asrc + ko + p * 32 * 512);
        rb[p] = *(const uint4*)(Bsrc + ko + p * 32 * 512);
      }
    }
    #pragma unroll
    for (int ck = 0; ck < 2; ++ck) {
      bf16x8 af[4], bfr[4];
      #pragma unroll
      for (int mi = 0; mi < 4; ++mi) {
        const int r = wr * 64 + mi * 16 + ln;
        af[mi] = *(const bf16x8*)&As[cur][r][((ck * 4 + lg) ^ (r & 7)) * 8];
      }
      #pragma unroll
      for (int ni = 0; ni < 4; ++ni) {
        const int r = wc * 64 + ni * 16 + ln;
        bfr[ni] = *(const bf16x8*)&Bs[cur][r][((ck * 4 + lg) ^ (r & 7)) * 8];
      }
      #pragma unroll
      for (int mi = 0; mi < 4; ++mi)
        #pragma unroll
        for (int ni = 0; ni < 4; ++ni)
          acc[mi][ni] = __builtin_amdgcn_mfma_f32_16x16x32_bf16(
              af[mi], bfr[ni], acc[mi][ni], 0, 0, 0);
    }
    if (kt < 7) {
      #pragma unroll
      for (int p = 0; p < 4; ++p) {
        *(uint4*)&As[cur ^ 1][srow + 32 * p][sw] = ra[p];
        *(uint4*)&Bs[cur ^ 1][srow + 32 * p][sw] = rb[p];
      }
      __syncthreads();
      cur ^= 1;
    }
  }

  TOUT* C = (TOUT*)gb.out[(wrow >> 9) - (gb.wrow0 >> 9)];
  const int nbase = wrow & 511;
  #pragma unroll
  for (int ni = 0; ni < 4; ++ni) {
    const int colw = wc * 64 + ni * 16 + ln;
    const float bv = bias[colw];
    const int col = nbase + colw;
    #pragma unroll
    for (int mi = 0; mi < 4; ++mi)
      #pragma unroll
      for (int r = 0; r < 4; ++r) {
        const int row = m0 + wr * 64 + mi * 16 + 4 * lg + r;
        const float val = acc[mi][ni][r] + bv;
        if constexpr (sizeof(TOUT) == 4) C[(size_t)row * 512 + col] = val;
        else                             C[(size_t)row * 512 + col] = f2bf(val);
      }
  }
}

// ---------------------------------------------------------------------------
// Flash attention: 512 threads = 8 waves x 32 Q-rows (QBLK=256), KVBLK=64,
// KV-split x2. grid 256 = exactly 1 block/CU -> 8 waves/CU = 2/SIMD
// deterministic (intra-block TLP; no inter-block LDS co-residency gamble).
// K/Kf/Vt double-buffered (48 KiB) + per-wave P_s (32 KiB) = 80 KiB LDS.
// Defer-max (THR=11, log2 domain), Q pre-scaled by SCALE*log2e.
// Writes unnormalized O (bf16) + (m,l) per row; combine kernel merges splits.
// ---------------------------------------------------------------------------
__global__ __launch_bounds__(512) void attn5(
    const u16* __restrict__ q2, const u16* __restrict__ k2,
    const u16* __restrict__ qf2, const u16* __restrict__ kf2,
    const u16* __restrict__ vtg, u16* __restrict__ opart,
    float2* __restrict__ mlbuf) {
  const int id = blockIdx.x;
  const int nid = (id & 7) * 32 + (id >> 3);   // XCD-bijective: 2 heads/XCD
  const int split = nid & 1;
  const int qt = (nid >> 1) & 7;
  const int bh = nid >> 4;
  const size_t base = (size_t)bh * 131072;
  const int kv0 = split * 1024;

  const u16* Q  = q2  + base;
  const u16* Qf = qf2 + base;
  u16* Op = opart + (size_t)split * 2097152 + base;

  const int t = threadIdx.x, wid = t >> 6, lane = t & 63;
  const int lg = lane >> 4, ln = lane & 15;
  const int r0 = qt * 256 + wid * 32;          // this wave's 32 Q rows (local)

  __shared__ u16 K_s [2][64][64];
  __shared__ u16 Kf_s[2][64][64];
  __shared__ u16 Vt_s[2][64][64];
  __shared__ u16 P_s [8][32][64];

  const int srow = t >> 3, sch = t & 7;        // 64 rows x 8 chunks, 1 uint4/thr
  const int sw = (sch ^ (srow & 7)) * 8;
  const u16* Ksrc  = k2  + base + (size_t)(kv0 + srow) * 64 + sch * 8;
  const u16* Kfsrc = kf2 + base + (size_t)(kv0 + srow) * 64 + sch * 8;
  const u16* Vsrc  = vtg + base + (size_t)srow * 2048 + kv0 + sch * 8;

  bf16x8 aq[2][4];
  #pragma unroll
  for (int mi = 0; mi < 2; ++mi) {
    const int row = r0 + mi * 16 + ln;
    aq[mi][0] = *(const bf16x8*)&Q [row * 64 +      lg * 8];
    aq[mi][1] = *(const bf16x8*)&Q [row * 64 + 32 + lg * 8];
    aq[mi][2] = *(const bf16x8*)&Qf[row * 64 +      lg * 8];
    aq[mi][3] = *(const bf16x8*)&Qf[row * 64 + 32 + lg * 8];
  }

  f32x4 oacc[2][4];
  #pragma unroll
  for (int mi = 0; mi < 2; ++mi)
    #pragma unroll
    for (int df = 0; df < 4; ++df)
      #pragma unroll
      for (int r = 0; r < 4; ++r) oacc[mi][df][r] = 0.0f;
  float m_run[2][4], l_par[2][4];
  #pragma unroll
  for (int mi = 0; mi < 2; ++mi)
    #pragma unroll
    for (int r = 0; r < 4; ++r) { m_run[mi][r] = -1e30f; l_par[mi][r] = 0.0f; }

  // prologue: stage tile 0
  uint4 rk = *(const uint4*)(Ksrc);
  uint4 rf = *(const uint4*)(Kfsrc);
  uint4 rv = *(const uint4*)(Vsrc);
  *(uint4*)&K_s [0][srow][sw] = rk;
  *(uint4*)&Kf_s[0][srow][sw] = rf;
  *(uint4*)&Vt_s[0][srow][sw] = rv;
  __syncthreads();

  int cur = 0;
  for (int kt = 0; kt < 16; ++kt) {
    if (kt < 15) {
      const int ko = (kt + 1) * 4096;
      rk = *(const uint4*)(Ksrc  + ko);
      rf = *(const uint4*)(Kfsrc + ko);
      rv = *(const uint4*)(Vsrc  + (kt + 1) * 64);
    }

    // ---- S = Q K^T + Qf Kf^T (pre-scaled, log2 domain) ----
    f32x4 s[2][4];
    #pragma unroll
    for (int cf = 0; cf < 4; ++cf) {
      const int n = cf * 16 + ln;
      const int sx = n & 7;
      bf16x8 b0 = *(const bf16x8*)&K_s [cur][n][((0 + lg) ^ sx) * 8];
      bf16x8 b1 = *(const bf16x8*)&K_s [cur][n][((4 + lg) ^ sx) * 8];
      bf16x8 b2 = *(const bf16x8*)&Kf_s[cur][n][((0 + lg) ^ sx) * 8];
      bf16x8 b3 = *(const bf16x8*)&Kf_s[cur][n][((4 + lg) ^ sx) * 8];
      #pragma unroll
      for (int mi = 0; mi < 2; ++mi) {
        f32x4 a;
        #pragma unroll
        for (int r = 0; r < 4; ++r) a[r] = 0.0f;
        a = __builtin_amdgcn_mfma_f32_16x16x32_bf16(aq[mi][0], b0, a, 0, 0, 0);
        a = __builtin_amdgcn_mfma_f32_16x16x32_bf16(aq[mi][1], b1, a, 0, 0, 0);
        a = __builtin_amdgcn_mfma_f32_16x16x32_bf16(aq[mi][2], b2, a, 0, 0, 0);
        a = __builtin_amdgcn_mfma_f32_16x16x32_bf16(aq[mi][3], b3, a, 0, 0, 0);
        s[mi][cf] = a;
      }
    }

    // ---- defer-max online softmax ----
    float smax[2][4];
    bool viol = false;
    #pragma unroll
    for (int mi = 0; mi < 2; ++mi)
      #pragma unroll
      for (int r = 0; r < 4; ++r) {
        smax[mi][r] = fmaxf(fmaxf(s[mi][0][r], s[mi][1][r]),
                            fmaxf(s[mi][2][r], s[mi][3][r]));
        viol = viol || (smax[mi][r] > m_run[mi][r] + 11.0f);
      }
    if (__any(viol)) {
      #pragma unroll
      for (int off = 1; off < 16; off <<= 1)
        #pragma unroll
        for (int mi = 0; mi < 2; ++mi)
          #pragma unroll
          for (int r = 0; r < 4; ++r)
            smax[mi][r] = fmaxf(smax[mi][r], __shfl_xor(smax[mi][r], off, 64));
      #pragma unroll
      for (int mi = 0; mi < 2; ++mi)
        #pragma unroll
        for (int r = 0; r < 4; ++r) {
          const float mnew = fmaxf(m_run[mi][r], smax[mi][r]);
          const float corr = exp2f(m_run[mi][r] - mnew);
          m_run[mi][r] = mnew;
          l_par[mi][r] *= corr;
          #pragma unroll
          for (int df = 0; df < 4; ++df) oacc[mi][df][r] *= corr;
        }
    }
    #pragma unroll
    for (int mi = 0; mi < 2; ++mi)
      #pragma unroll
      for (int cf = 0; cf < 4; ++cf) {
        const int col = cf * 16 + ln;
        #pragma unroll
        for (int r = 0; r < 4; ++r) {
          const int rr = 4 * lg + r;
          const float p = exp2f(s[mi][cf][r] - m_run[mi][r]);
          l_par[mi][r] += p;
          P_s[wid][mi * 16 + rr][col ^ ((rr & 7) * 8)] =
              __builtin_bit_cast(u16, __float2bfloat16(p));
        }
      }

    // ---- O += P @ V ----
    #pragma unroll
    for (int kc = 0; kc < 2; ++kc) {
      const int kk = kc * 32 + lg * 8;
      bf16x8 ap0 = *(const bf16x8*)&P_s[wid][ln]     [kk ^ ((ln & 7) * 8)];
      bf16x8 ap1 = *(const bf16x8*)&P_s[wid][16 + ln][kk ^ ((ln & 7) * 8)];
      #pragma unroll
      for (int df = 0; df < 4; ++df) {
        const int n = df * 16 + ln;
        bf16x8 bv = *(const bf16x8*)&Vt_s[cur][n][((kc * 4 + lg) ^ (n & 7)) * 8];
        oacc[0][df] = __builtin_amdgcn_mfma_f32_16x16x32_bf16(ap0, bv, oacc[0][df], 0, 0, 0);
        oacc[1][df] = __builtin_amdgcn_mfma_f32_16x16x32_bf16(ap1, bv, oacc[1][df], 0, 0, 0);
      }
    }

    if (kt < 15) {
      *(uint4*)&K_s [cur ^ 1][srow][sw] = rk;
      *(uint4*)&Kf_s[cur ^ 1][srow][sw] = rf;
      *(uint4*)&Vt_s[cur ^ 1][srow][sw] = rv;
      __syncthreads();
      cur ^= 1;
    }
  }

  // epilogue: reduce l across 16 lanes; write unnormalized O + (m,l)
  #pragma unroll
  for (int off = 1; off < 16; off <<= 1)
    #pragma unroll
    for (int mi = 0; mi < 2; ++mi)
      #pragma unroll
      for (int r = 0; r < 4; ++r)
        l_par[mi][r] += __shfl_xor(l_par[mi][r], off, 64);

  #pragma unroll
  for (int mi = 0; mi < 2; ++mi)
    #pragma unroll
    for (int df = 0; df < 4; ++df)
      #pragma unroll
      for (int r = 0; r < 4; ++r) {
        const int row = r0 + mi * 16 + 4 * lg + r;
        const int col = df * 16 + ln;
        Op[(size_t)row * 64 + col] = f2bf(oacc[mi][df][r]);
      }
  if (ln == 0) {
    #pragma unroll
    for (int mi = 0; mi < 2; ++mi)
      #pragma unroll
      for (int r = 0; r < 4; ++r) {
        const int grow = bh * 2048 + r0 + mi * 16 + 4 * lg + r;
        mlbuf[split * 32768 + grow] = make_float2(m_run[mi][r], l_par[mi][r]);
      }
  }
}

// ---------------------------------------------------------------------------
// Combine the two KV-split partials: out = sum_i O_i*a_i / sum_i l_i*a_i.
// grid 1024 x 256, 8 cols/thread.
// ---------------------------------------------------------------------------
__global__ __launch_bounds__(256) void combine(
    const u16* __restrict__ opart, const float2* __restrict__ mlbuf,
    u16* __restrict__ att) {
  const int gid = blockIdx.x * 256 + threadIdx.x;
  const int row = gid >> 3, c8 = (gid & 7) * 8;
  const float2 ml1 = mlbuf[row];
  const float2 ml2 = mlbuf[32768 + row];
  const float mx = fmaxf(ml1.x, ml2.x);
  const float a1 = exp2f(ml1.x - mx), a2 = exp2f(ml2.x - mx);
  const float inv = 1.0f / (ml1.y * a1 + ml2.y * a2);
  const float w1 = a1 * inv, w2 = a2 * inv;
  uint4 o1 = *(const uint4*)&opart[(size_t)row * 64 + c8];
  uint4 o2 = *(const uint4*)&opart[2097152 + (size_t)row * 64 + c8];
  const u16* p1 = (const u16*)&o1;
  const u16* p2 = (const u16*)&o2;
  alignas(16) u16 ot[8];
  #pragma unroll
  for (int i = 0; i < 8; ++i)
    ot[i] = f2bf(bf2f(p1[i]) * w1 + bf2f(p2[i]) * w2);
  *(uint4*)&att[(size_t)row * 64 + c8] = *(const uint4*)ot;
}

// ---------------------------------------------------------------------------
extern "C" void kernel_launch(void* const* d_in, const int* in_sizes, int n_in,
                              void* d_out, int out_size, void* d_ws, size_t ws_size,
                              hipStream_t stream) {
  const float* x    = (const float*)d_in[0];
  const float* xk   = (const float*)d_in[1];
  const float* Wv   = (const float*)d_in[2];  const float* bv   = (const float*)d_in[3];
  const float* Wk   = (const float*)d_in[4];  const float* bk   = (const float*)d_in[5];
  const float* Wq   = (const float*)d_in[6];  const float* bq   = (const float*)d_in[7];
  const float* Wkf  = (const float*)d_in[8];  const float* bkf  = (const float*)d_in[9];
  const float* Wqf  = (const float*)d_in[10]; const float* bqf  = (const float*)d_in[11];
  const float* Wq2  = (const float*)d_in[12]; const float* bq2  = (const float*)d_in[13];
  const float* Wk2  = (const float*)d_in[14]; const float* bk2  = (const float*)d_in[15];
  const float* Wqf2 = (const float*)d_in[16]; const float* bqf2 = (const float*)d_in[17];
  const float* Wkf2 = (const float*)d_in[18]; const float* bkf2 = (const float*)d_in[19];
  const float* Wo   = (const float*)d_in[20]; const float* bo   = (const float*)d_in[21];

  u16* ws = (u16*)d_ws;
  u16* Wt = ws;                                   // 10 x 262144 u16 (5120x512)
  float* biasP = (float*)(ws + 2621440);          // 5120 f32
  u16* bufs = ws + 2621440 + 10240;
  const size_t BUF = 2097152;
  u16* v1  = bufs + 0 * BUF;   // stage-1 v; later att (combine output)
  u16* k1  = bufs + 1 * BUF;   // stage-1 k
  u16* q1  = bufs + 2 * BUF;   // stage-1 q; later vt (dead after stage-2)
  u16* kf1 = bufs + 3 * BUF;   // stage-1 kf; later O_part split 0
  u16* qf1 = bufs + 4 * BUF;   // stage-1 qf; later O_part split 1 (contig)
  u16* q2  = bufs + 5 * BUF;   // xb, then stage-2 q
  u16* k2  = bufs + 6 * BUF;   // xkb, then stage-2 k
  u16* qf2 = bufs + 7 * BUF;
  u16* kf2 = bufs + 8 * BUF;
  float2* mlbuf = (float2*)(bufs + 9 * BUF);      // 2 x 32768 float2

  cvt_bf16<<<dim3(1024, 2), 256, 0, stream>>>(x, xk, q2, k2);

  TPtrs tp;
  tp.p[0] = Wv;  tp.p[1] = Wk;  tp.p[2] = Wq;   tp.p[3] = Wkf;  tp.p[4] = Wqf;
  tp.p[5] = Wq2; tp.p[6] = Wk2; tp.p[7] = Wqf2; tp.p[8] = Wkf2; tp.p[9] = Wo;
  transposeW<<<dim3(8, 8, 10), 256, 0, stream>>>(tp, Wt);

  BPtrs bp;
  bp.p[0] = bv;  bp.p[1] = bk;  bp.p[2] = bq;   bp.p[3] = bkf;  bp.p[4] = bqf;
  bp.p[5] = bq2; bp.p[6] = bk2; bp.p[7] = bqf2; bp.p[8] = bkf2; bp.p[9] = bo;
  biasPack<<<dim3(10), 512, 0, stream>>>(bp, biasP);

  // stage-1 fused (x and xk in one launch): v,k,q from x; kf,qf from xk
  GemmBatch g1 = {};
  g1.A[0] = q2;  g1.Ax = k2;  g1.xsplit = 12;
  g1.out[0] = v1; g1.out[1] = k1; g1.out[2] = q1; g1.out[3] = kf1; g1.out[4] = qf1;
  g1.wrow0 = 0; g1.zstride = 0;
  gemm3<u16><<<dim3(20, 32, 1), 256, 0, stream>>>(g1, Wt, biasP);

  // stage-2 batched: {q1,k1,qf1,kf1} @ {Wq2,Wk2,Wqf2,Wkf2} -> {q2,k2,qf2,kf2}
  GemmBatch g3 = {};
  g3.A[0] = q1; g3.A[1] = k1; g3.A[2] = qf1; g3.A[3] = kf1;
  g3.Ax = q1; g3.xsplit = 100;
  g3.out[0] = q2; g3.out[1] = k2; g3.out[2] = qf2; g3.out[3] = kf2;
  g3.wrow0 = 2560; g3.zstride = 512;
  gemm3<u16><<<dim3(4, 32, 4), 256, 0, stream>>>(g3, Wt, biasP);

  // V transpose per head-block (v1 -> q1; q1 dead after stage-2)
  transposeV<<<dim3(32, 16), 256, 0, stream>>>(v1, q1);

  // attention: 256 blocks x 512 threads (1/CU, 8 waves), KV-split x2
  attn5<<<dim3(256), 512, 0, stream>>>(q2, k2, qf2, kf2, q1, kf1, mlbuf);

  // combine partials -> att (v1)
  combine<<<dim3(1024), 256, 0, stream>>>(kf1, mlbuf, v1);

  // final: att @ Wo + bo -> d_out (fp32)
  GemmBatch g4 = {};
  g4.A[0] = v1; g4.Ax = v1; g4.xsplit = 100;
  g4.out[0] = d_out;
  g4.wrow0 = 4608; g4.zstride = 0;
  gemm3<float><<<dim3(4, 32, 1), 256, 0, stream>>>(g4, Wt, biasP);
}

// Round 9
// 118.803 us; speedup vs baseline: 1.1935x; 1.0012x over previous
//
#include <hip/hip_runtime.h>
#include <hip/hip_bf16.h>

typedef unsigned short u16;
typedef unsigned int   u32;
typedef __attribute__((ext_vector_type(8))) short bf16x8;
typedef __attribute__((ext_vector_type(4))) float f32x4;

#define SCALE 0.08838834764831845f                 // 1/sqrt(2*64)
#define SCLOG 0.12752040542575836f                 // SCALE * log2(e)

__device__ inline u16 f2bf(float f) {
  u32 u = __builtin_bit_cast(u32, f);
  u = (u + 0x7FFFu + ((u >> 16) & 1u)) >> 16;      // RNE
  return (u16)u;
}
__device__ inline float bf2f(u16 b) {
  u32 u = (u32)b << 16;
  return __builtin_bit_cast(float, u);
}

// ---------------------------------------------------------------------------
// fp32 -> bf16 bulk convert (x and x_knowledge). grid (1024, 2), 8 elems/thr.
// ---------------------------------------------------------------------------
__global__ __launch_bounds__(256) void cvt_bf16(const float* __restrict__ a,
                                                const float* __restrict__ b,
                                                u16* __restrict__ oa,
                                                u16* __restrict__ ob) {
  const float* in = blockIdx.y ? b : a;
  u16* out = blockIdx.y ? ob : oa;
  const int i = (blockIdx.x * 256 + threadIdx.x) * 8;
  float4 f0 = *(const float4*)(in + i);
  float4 f1 = *(const float4*)(in + i + 4);
  alignas(16) u16 t[8] = {f2bf(f0.x), f2bf(f0.y), f2bf(f0.z), f2bf(f0.w),
                          f2bf(f1.x), f2bf(f1.y), f2bf(f1.z), f2bf(f1.w)};
  *(uint4*)(out + i) = *(const uint4*)t;
}

// ---------------------------------------------------------------------------
// Weight transpose Wt[z][n][k] = W[z][k][n] (fp32->bf16); slots 5,7 scaled
// by SCALE*log2e (folds attn scale + exp->exp2 into Q,Qf projections).
// ---------------------------------------------------------------------------
struct TPtrs { const float* p[10]; };

__global__ __launch_bounds__(256) void transposeW(TPtrs ptrs, u16* __restrict__ out) {
  __shared__ u16 ts[64][65];
  const float sc = (blockIdx.z == 5 || blockIdx.z == 7) ? SCLOG : 1.0f;
  const float* in = ptrs.p[blockIdx.z];
  u16* o = out + (size_t)blockIdx.z * 262144;
  const int t = threadIdx.x;
  const int k0 = blockIdx.y * 64, n0 = blockIdx.x * 64;
  for (int pp = 0; pp < 16; ++pp) {
    int id = t + 256 * pp; int r = id >> 6, c = id & 63;
    ts[r][c] = f2bf(in[(size_t)(k0 + r) * 512 + n0 + c] * sc);
  }
  __syncthreads();
  for (int pp = 0; pp < 16; ++pp) {
    int id = t + 256 * pp; int r = id >> 6, c = id & 63;
    o[(size_t)(n0 + r) * 512 + k0 + c] = ts[c][r];
  }
}

struct BPtrs { const float* p[10]; };

__global__ __launch_bounds__(512) void biasPack(BPtrs bp, float* __restrict__ out) {
  const int z = blockIdx.x, n = threadIdx.x;
  const float sc = (z == 5 || z == 7) ? SCLOG : 1.0f;
  out[z * 512 + n] = bp.p[z][n] * sc;
}

// ---------------------------------------------------------------------------
// Per-head V transpose: v1 (2048,64) -> vt (64,2048) per head-block.
// grid (32,16).
// ---------------------------------------------------------------------------
__global__ __launch_bounds__(256) void transposeV(const u16* __restrict__ v1,
                                                  u16* __restrict__ vt) {
  __shared__ u16 ts[64][65];
  const size_t base = (size_t)blockIdx.y * 131072;
  const u16* in = v1 + base;
  u16* out = vt + base;
  const int l0 = blockIdx.x * 64;
  const int t = threadIdx.x;
  const int r = t >> 3, c8 = (t & 7) * 8;
  for (int pp = 0; pp < 2; ++pp) {
    int rr = r + pp * 32;
    *(uint4*)&ts[rr][c8] = *(const uint4*)&in[(size_t)(l0 + rr) * 64 + c8];
  }
  __syncthreads();
  for (int pp = 0; pp < 2; ++pp) {
    int d = r + pp * 32;
    alignas(16) u16 tmp[8];
    #pragma unroll
    for (int i = 0; i < 8; ++i) tmp[i] = ts[c8 + i][d];
    *(uint4*)&out[(size_t)d * 2048 + l0 + c8] = *(const uint4*)tmp;
  }
}

// ---------------------------------------------------------------------------
// GEMM: 128x128 tile, BK=64, 4 waves (2x2) of 64x64. 2-phase dbuf, reg-staged,
// XOR-swizzled LDS. Wt is one (5120 x 512) matrix; wrow = wrow0+z*zstride+
// blockIdx.x*128. A switches to Ax at tile xsplit (stage-1 fusion).
// ---------------------------------------------------------------------------
struct GemmBatch {
  const u16* A[4];
  const u16* Ax;
  int xsplit;
  void* out[5];        // indexed by (wrow>>9) - (wrow0>>9)
  int wrow0, zstride;
};

template <typename TOUT>
__global__ __launch_bounds__(256, 2) void gemm3(GemmBatch gb,
    const u16* __restrict__ Wt, const float* __restrict__ biasP) {
  const int tx = blockIdx.x, z = blockIdx.z;
  const u16* A = (tx < gb.xsplit) ? gb.A[z] : gb.Ax;
  const int wrow = gb.wrow0 + z * gb.zstride + tx * 128;
  const int m0 = blockIdx.y * 128;
  const u16* B = Wt + (size_t)wrow * 512;
  const float* bias = biasP + wrow;

  const int t = threadIdx.x, wid = t >> 6, lane = t & 63;
  const int lg = lane >> 4, ln = lane & 15;
  const int wr = wid >> 1, wc = wid & 1;

  __shared__ u16 As[2][128][64];
  __shared__ u16 Bs[2][128][64];

  const int srow = t >> 3, sch = t & 7;
  const int sw = (sch ^ (srow & 7)) * 8;
  const u16* Asrc = A + (size_t)(m0 + srow) * 512 + sch * 8;
  const u16* Bsrc = B + (size_t)srow * 512 + sch * 8;

  uint4 ra[4], rb[4];
  #pragma unroll
  for (int p = 0; p < 4; ++p) {
    ra[p] = *(const uint4*)(Asrc + p * 32 * 512);
    rb[p] = *(const uint4*)(Bsrc + p * 32 * 512);
  }
  #pragma unroll
  for (int p = 0; p < 4; ++p) {
    *(uint4*)&As[0][srow + 32 * p][sw] = ra[p];
    *(uint4*)&Bs[0][srow + 32 * p][sw] = rb[p];
  }
  __syncthreads();

  f32x4 acc[4][4];
  #pragma unroll
  for (int i = 0; i < 4; ++i)
    #pragma unroll
    for (int j = 0; j < 4; ++j)
      #pragma unroll
      for (int r = 0; r < 4; ++r) acc[i][j][r] = 0.0f;

  int cur = 0;
  for (int kt = 0; kt < 8; ++kt) {
    if (kt < 7) {
      const int ko = (kt + 1) * 64;
      #pragma unroll
      for (int p = 0; p < 4; ++p) {
        ra[p] = *(const uint4*)(Asrc + ko + p * 32 * 512);
        rb[p] = *(const uint4*)(Bsrc + ko + p * 32 * 512);
      }
    }
    #pragma unroll
    for (int ck = 0; ck < 2; ++ck) {
      bf16x8 af[4], bfr[4];
      #pragma unroll
      for (int mi = 0; mi < 4; ++mi) {
        const int r = wr * 64 + mi * 16 + ln;
        af[mi] = *(const bf16x8*)&As[cur][r][((ck * 4 + lg) ^ (r & 7)) * 8];
      }
      #pragma unroll
      for (int ni = 0; ni < 4; ++ni) {
        const int r = wc * 64 + ni * 16 + ln;
        bfr[ni] = *(const bf16x8*)&Bs[cur][r][((ck * 4 + lg) ^ (r & 7)) * 8];
      }
      #pragma unroll
      for (int mi = 0; mi < 4; ++mi)
        #pragma unroll
        for (int ni = 0; ni < 4; ++ni)
          acc[mi][ni] = __builtin_amdgcn_mfma_f32_16x16x32_bf16(
              af[mi], bfr[ni], acc[mi][ni], 0, 0, 0);
    }
    if (kt < 7) {
      #pragma unroll
      for (int p = 0; p < 4; ++p) {
        *(uint4*)&As[cur ^ 1][srow + 32 * p][sw] = ra[p];
        *(uint4*)&Bs[cur ^ 1][srow + 32 * p][sw] = rb[p];
      }
      __syncthreads();
      cur ^= 1;
    }
  }

  TOUT* C = (TOUT*)gb.out[(wrow >> 9) - (gb.wrow0 >> 9)];
  const int nbase = wrow & 511;
  #pragma unroll
  for (int ni = 0; ni < 4; ++ni) {
    const int colw = wc * 64 + ni * 16 + ln;
    const float bv = bias[colw];
    const int col = nbase + colw;
    #pragma unroll
    for (int mi = 0; mi < 4; ++mi)
      #pragma unroll
      for (int r = 0; r < 4; ++r) {
        const int row = m0 + wr * 64 + mi * 16 + 4 * lg + r;
        const float val = acc[mi][ni][r] + bv;
        if constexpr (sizeof(TOUT) == 4) C[(size_t)row * 512 + col] = val;
        else                             C[(size_t)row * 512 + col] = f2bf(val);
      }
  }
}

// ---------------------------------------------------------------------------
// Flash attention: 512 threads = 8 waves x 32 Q-rows (QBLK=256), KVBLK=64,
// KV-split x2. grid 256 = exactly 1 block/CU -> 8 waves/CU = 2/SIMD
// deterministic (intra-block TLP; no inter-block LDS co-residency gamble).
// K/Kf/Vt double-buffered (48 KiB) + per-wave P_s (32 KiB) = 80 KiB LDS.
// Defer-max (THR=11, log2 domain), Q pre-scaled by SCALE*log2e.
// Writes unnormalized O (bf16) + (m,l) per row; combine kernel merges splits.
// ---------------------------------------------------------------------------
__global__ __launch_bounds__(512) void attn5(
    const u16* __restrict__ q2, const u16* __restrict__ k2,
    const u16* __restrict__ qf2, const u16* __restrict__ kf2,
    const u16* __restrict__ vtg, u16* __restrict__ opart,
    float2* __restrict__ mlbuf) {
  const int id = blockIdx.x;
  const int nid = (id & 7) * 32 + (id >> 3);   // XCD-bijective: 2 heads/XCD
  const int split = nid & 1;
  const int qt = (nid >> 1) & 7;
  const int bh = nid >> 4;
  const size_t base = (size_t)bh * 131072;
  const int kv0 = split * 1024;

  const u16* Q  = q2  + base;
  const u16* Qf = qf2 + base;
  u16* Op = opart + (size_t)split * 2097152 + base;

  const int t = threadIdx.x, wid = t >> 6, lane = t & 63;
  const int lg = lane >> 4, ln = lane & 15;
  const int r0 = qt * 256 + wid * 32;          // this wave's 32 Q rows (local)

  __shared__ u16 K_s [2][64][64];
  __shared__ u16 Kf_s[2][64][64];
  __shared__ u16 Vt_s[2][64][64];
  __shared__ u16 P_s [8][32][64];

  const int srow = t >> 3, sch = t & 7;        // 64 rows x 8 chunks, 1 uint4/thr
  const int sw = (sch ^ (srow & 7)) * 8;
  const u16* Ksrc  = k2  + base + (size_t)(kv0 + srow) * 64 + sch * 8;
  const u16* Kfsrc = kf2 + base + (size_t)(kv0 + srow) * 64 + sch * 8;
  const u16* Vsrc  = vtg + base + (size_t)srow * 2048 + kv0 + sch * 8;

  bf16x8 aq[2][4];
  #pragma unroll
  for (int mi = 0; mi < 2; ++mi) {
    const int row = r0 + mi * 16 + ln;
    aq[mi][0] = *(const bf16x8*)&Q [row * 64 +      lg * 8];
    aq[mi][1] = *(const bf16x8*)&Q [row * 64 + 32 + lg * 8];
    aq[mi][2] = *(const bf16x8*)&Qf[row * 64 +      lg * 8];
    aq[mi][3] = *(const bf16x8*)&Qf[row * 64 + 32 + lg * 8];
  }

  f32x4 oacc[2][4];
  #pragma unroll
  for (int mi = 0; mi < 2; ++mi)
    #pragma unroll
    for (int df = 0; df < 4; ++df)
      #pragma unroll
      for (int r = 0; r < 4; ++r) oacc[mi][df][r] = 0.0f;
  float m_run[2][4], l_par[2][4];
  #pragma unroll
  for (int mi = 0; mi < 2; ++mi)
    #pragma unroll
    for (int r = 0; r < 4; ++r) { m_run[mi][r] = -1e30f; l_par[mi][r] = 0.0f; }

  // prologue: stage tile 0
  uint4 rk = *(const uint4*)(Ksrc);
  uint4 rf = *(const uint4*)(Kfsrc);
  uint4 rv = *(const uint4*)(Vsrc);
  *(uint4*)&K_s [0][srow][sw] = rk;
  *(uint4*)&Kf_s[0][srow][sw] = rf;
  *(uint4*)&Vt_s[0][srow][sw] = rv;
  __syncthreads();

  int cur = 0;
  for (int kt = 0; kt < 16; ++kt) {
    if (kt < 15) {
      const int ko = (kt + 1) * 4096;
      rk = *(const uint4*)(Ksrc  + ko);
      rf = *(const uint4*)(Kfsrc + ko);
      rv = *(const uint4*)(Vsrc  + (kt + 1) * 64);
    }

    // ---- S = Q K^T + Qf Kf^T (pre-scaled, log2 domain) ----
    f32x4 s[2][4];
    #pragma unroll
    for (int cf = 0; cf < 4; ++cf) {
      const int n = cf * 16 + ln;
      const int sx = n & 7;
      bf16x8 b0 = *(const bf16x8*)&K_s [cur][n][((0 + lg) ^ sx) * 8];
      bf16x8 b1 = *(const bf16x8*)&K_s [cur][n][((4 + lg) ^ sx) * 8];
      bf16x8 b2 = *(const bf16x8*)&Kf_s[cur][n][((0 + lg) ^ sx) * 8];
      bf16x8 b3 = *(const bf16x8*)&Kf_s[cur][n][((4 + lg) ^ sx) * 8];
      #pragma unroll
      for (int mi = 0; mi < 2; ++mi) {
        f32x4 a;
        #pragma unroll
        for (int r = 0; r < 4; ++r) a[r] = 0.0f;
        a = __builtin_amdgcn_mfma_f32_16x16x32_bf16(aq[mi][0], b0, a, 0, 0, 0);
        a = __builtin_amdgcn_mfma_f32_16x16x32_bf16(aq[mi][1], b1, a, 0, 0, 0);
        a = __builtin_amdgcn_mfma_f32_16x16x32_bf16(aq[mi][2], b2, a, 0, 0, 0);
        a = __builtin_amdgcn_mfma_f32_16x16x32_bf16(aq[mi][3], b3, a, 0, 0, 0);
        s[mi][cf] = a;
      }
    }

    // ---- defer-max online softmax ----
    float smax[2][4];
    bool viol = false;
    #pragma unroll
    for (int mi = 0; mi < 2; ++mi)
      #pragma unroll
      for (int r = 0; r < 4; ++r) {
        smax[mi][r] = fmaxf(fmaxf(s[mi][0][r], s[mi][1][r]),
                            fmaxf(s[mi][2][r], s[mi][3][r]));
        viol = viol || (smax[mi][r] > m_run[mi][r] + 11.0f);
      }
    if (__any(viol)) {
      #pragma unroll
      for (int off = 1; off < 16; off <<= 1)
        #pragma unroll
        for (int mi = 0; mi < 2; ++mi)
          #pragma unroll
          for (int r = 0; r < 4; ++r)
            smax[mi][r] = fmaxf(smax[mi][r], __shfl_xor(smax[mi][r], off, 64));
      #pragma unroll
      for (int mi = 0; mi < 2; ++mi)
        #pragma unroll
        for (int r = 0; r < 4; ++r) {
          const float mnew = fmaxf(m_run[mi][r], smax[mi][r]);
          const float corr = exp2f(m_run[mi][r] - mnew);
          m_run[mi][r] = mnew;
          l_par[mi][r] *= corr;
          #pragma unroll
          for (int df = 0; df < 4; ++df) oacc[mi][df][r] *= corr;
        }
    }
    #pragma unroll
    for (int mi = 0; mi < 2; ++mi)
      #pragma unroll
      for (int cf = 0; cf < 4; ++cf) {
        const int col = cf * 16 + ln;
        #pragma unroll
        for (int r = 0; r < 4; ++r) {
          const int rr = 4 * lg + r;
          const float p = exp2f(s[mi][cf][r] - m_run[mi][r]);
          l_par[mi][r] += p;
          P_s[wid][mi * 16 + rr][col ^ ((rr & 7) * 8)] =
              __builtin_bit_cast(u16, __float2bfloat16(p));
        }
      }

    // ---- O += P @ V ----
    #pragma unroll
    for (int kc = 0; kc < 2; ++kc) {
      const int kk = kc * 32 + lg * 8;
      bf16x8 ap0 = *(const bf16x8*)&P_s[wid][ln]     [kk ^ ((ln & 7) * 8)];
      bf16x8 ap1 = *(const bf16x8*)&P_s[wid][16 + ln][kk ^ ((ln & 7) * 8)];
      #pragma unroll
      for (int df = 0; df < 4; ++df) {
        const int n = df * 16 + ln;
        bf16x8 bv = *(const bf16x8*)&Vt_s[cur][n][((kc * 4 + lg) ^ (n & 7)) * 8];
        oacc[0][df] = __builtin_amdgcn_mfma_f32_16x16x32_bf16(ap0, bv, oacc[0][df], 0, 0, 0);
        oacc[1][df] = __builtin_amdgcn_mfma_f32_16x16x32_bf16(ap1, bv, oacc[1][df], 0, 0, 0);
      }
    }

    if (kt < 15) {
      *(uint4*)&K_s [cur ^ 1][srow][sw] = rk;
      *(uint4*)&Kf_s[cur ^ 1][srow][sw] = rf;
      *(uint4*)&Vt_s[cur ^ 1][srow][sw] = rv;
      __syncthreads();
      cur ^= 1;
    }
  }

  // epilogue: reduce l across 16 lanes; write unnormalized O + (m,l)
  #pragma unroll
  for (int off = 1; off < 16; off <<= 1)
    #pragma unroll
    for (int mi = 0; mi < 2; ++mi)
      #pragma unroll
      for (int r = 0; r < 4; ++r)
        l_par[mi][r] += __shfl_xor(l_par[mi][r], off, 64);

  #pragma unroll
  for (int mi = 0; mi < 2; ++mi)
    #pragma unroll
    for (int df = 0; df < 4; ++df)
      #pragma unroll
      for (int r = 0; r < 4; ++r) {
        const int row = r0 + mi * 16 + 4 * lg + r;
        const int col = df * 16 + ln;
        Op[(size_t)row * 64 + col] = f2bf(oacc[mi][df][r]);
      }
  if (ln == 0) {
    #pragma unroll
    for (int mi = 0; mi < 2; ++mi)
      #pragma unroll
      for (int r = 0; r < 4; ++r) {
        const int grow = bh * 2048 + r0 + mi * 16 + 4 * lg + r;
        mlbuf[split * 32768 + grow] = make_float2(m_run[mi][r], l_par[mi][r]);
      }
  }
}

// ---------------------------------------------------------------------------
// Combine the two KV-split partials: out = sum_i O_i*a_i / sum_i l_i*a_i.
// grid 1024 x 256, 8 cols/thread.
// ---------------------------------------------------------------------------
__global__ __launch_bounds__(256) void combine(
    const u16* __restrict__ opart, const float2* __restrict__ mlbuf,
    u16* __restrict__ att) {
  const int gid = blockIdx.x * 256 + threadIdx.x;
  const int row = gid >> 3, c8 = (gid & 7) * 8;
  const float2 ml1 = mlbuf[row];
  const float2 ml2 = mlbuf[32768 + row];
  const float mx = fmaxf(ml1.x, ml2.x);
  const float a1 = exp2f(ml1.x - mx), a2 = exp2f(ml2.x - mx);
  const float inv = 1.0f / (ml1.y * a1 + ml2.y * a2);
  const float w1 = a1 * inv, w2 = a2 * inv;
  uint4 o1 = *(const uint4*)&opart[(size_t)row * 64 + c8];
  uint4 o2 = *(const uint4*)&opart[2097152 + (size_t)row * 64 + c8];
  const u16* p1 = (const u16*)&o1;
  const u16* p2 = (const u16*)&o2;
  alignas(16) u16 ot[8];
  #pragma unroll
  for (int i = 0; i < 8; ++i)
    ot[i] = f2bf(bf2f(p1[i]) * w1 + bf2f(p2[i]) * w2);
  *(uint4*)&att[(size_t)row * 64 + c8] = *(const uint4*)ot;
}

// ---------------------------------------------------------------------------
extern "C" void kernel_launch(void* const* d_in, const int* in_sizes, int n_in,
                              void* d_out, int out_size, void* d_ws, size_t ws_size,
                              hipStream_t stream) {
  const float* x    = (const float*)d_in[0];
  const float* xk   = (const float*)d_in[1];
  const float* Wv   = (const float*)d_in[2];  const float* bv   = (const float*)d_in[3];
  const float* Wk   = (const float*)d_in[4];  const float* bk   = (const float*)d_in[5];
  const float* Wq   = (const float*)d_in[6];  const float* bq   = (const float*)d_in[7];
  const float* Wkf  = (const float*)d_in[8];  const float* bkf  = (const float*)d_in[9];
  const float* Wqf  = (const float*)d_in[10]; const float* bqf  = (const float*)d_in[11];
  const float* Wq2  = (const float*)d_in[12]; const float* bq2  = (const float*)d_in[13];
  const float* Wk2  = (const float*)d_in[14]; const float* bk2  = (const float*)d_in[15];
  const float* Wqf2 = (const float*)d_in[16]; const float* bqf2 = (const float*)d_in[17];
  const float* Wkf2 = (const float*)d_in[18]; const float* bkf2 = (const float*)d_in[19];
  const float* Wo   = (const float*)d_in[20]; const float* bo   = (const float*)d_in[21];

  u16* ws = (u16*)d_ws;
  u16* Wt = ws;                                   // 10 x 262144 u16 (5120x512)
  float* biasP = (float*)(ws + 2621440);          // 5120 f32
  u16* bufs = ws + 2621440 + 10240;
  const size_t BUF = 2097152;
  u16* v1  = bufs + 0 * BUF;   // stage-1 v; later att (combine output)
  u16* k1  = bufs + 1 * BUF;   // stage-1 k
  u16* q1  = bufs + 2 * BUF;   // stage-1 q; later vt (dead after stage-2)
  u16* kf1 = bufs + 3 * BUF;   // stage-1 kf; later O_part split 0
  u16* qf1 = bufs + 4 * BUF;   // stage-1 qf; later O_part split 1 (contig)
  u16* q2  = bufs + 5 * BUF;   // xb, then stage-2 q
  u16* k2  = bufs + 6 * BUF;   // xkb, then stage-2 k
  u16* qf2 = bufs + 7 * BUF;
  u16* kf2 = bufs + 8 * BUF;
  float2* mlbuf = (float2*)(bufs + 9 * BUF);      // 2 x 32768 float2

  cvt_bf16<<<dim3(1024, 2), 256, 0, stream>>>(x, xk, q2, k2);

  TPtrs tp;
  tp.p[0] = Wv;  tp.p[1] = Wk;  tp.p[2] = Wq;   tp.p[3] = Wkf;  tp.p[4] = Wqf;
  tp.p[5] = Wq2; tp.p[6] = Wk2; tp.p[7] = Wqf2; tp.p[8] = Wkf2; tp.p[9] = Wo;
  transposeW<<<dim3(8, 8, 10), 256, 0, stream>>>(tp, Wt);

  BPtrs bp;
  bp.p[0] = bv;  bp.p[1] = bk;  bp.p[2] = bq;   bp.p[3] = bkf;  bp.p[4] = bqf;
  bp.p[5] = bq2; bp.p[6] = bk2; bp.p[7] = bqf2; bp.p[8] = bkf2; bp.p[9] = bo;
  biasPack<<<dim3(10), 512, 0, stream>>>(bp, biasP);

  // stage-1 fused (x and xk in one launch): v,k,q from x; kf,qf from xk
  GemmBatch g1 = {};
  g1.A[0] = q2;  g1.Ax = k2;  g1.xsplit = 12;
  g1.out[0] = v1; g1.out[1] = k1; g1.out[2] = q1; g1.out[3] = kf1; g1.out[4] = qf1;
  g1.wrow0 = 0; g1.zstride = 0;
  gemm3<u16><<<dim3(20, 32, 1), 256, 0, stream>>>(g1, Wt, biasP);

  // stage-2 batched: {q1,k1,qf1,kf1} @ {Wq2,Wk2,Wqf2,Wkf2} -> {q2,k2,qf2,kf2}
  GemmBatch g3 = {};
  g3.A[0] = q1; g3.A[1] = k1; g3.A[2] = qf1; g3.A[3] = kf1;
  g3.Ax = q1; g3.xsplit = 100;
  g3.out[0] = q2; g3.out[1] = k2; g3.out[2] = qf2; g3.out[3] = kf2;
  g3.wrow0 = 2560; g3.zstride = 512;
  gemm3<u16><<<dim3(4, 32, 4), 256, 0, stream>>>(g3, Wt, biasP);

  // V transpose per head-block (v1 -> q1; q1 dead after stage-2)
  transposeV<<<dim3(32, 16), 256, 0, stream>>>(v1, q1);

  // attention: 256 blocks x 512 threads (1/CU, 8 waves), KV-split x2
  attn5<<<dim3(256), 512, 0, stream>>>(q2, k2, qf2, kf2, q1, kf1, mlbuf);

  // combine partials -> att (v1)
  combine<<<dim3(1024), 256, 0, stream>>>(kf1, mlbuf, v1);

  // final: att @ Wo + bo -> d_out (fp32)
  GemmBatch g4 = {};
  g4.A[0] = v1; g4.Ax = v1; g4.xsplit = 100;
  g4.out[0] = d_out;
  g4.wrow0 = 4608; g4.zstride = 0;
  gemm3<float><<<dim3(4, 32, 1), 256, 0, stream>>>(g4, Wt, biasP);
}